// Round 14
// baseline (6487.114 us; speedup 1.0000x reference)
//
#include <hip/hip_runtime.h>

#define MSCOPE __HIP_MEMORY_SCOPE_AGENT

// ---------------- model dims ----------------
// V=50000 E=128 H=160 D=196 A=224 BN=56, B=32, Tin=256, Ttgt=100
// X layouts (TRANSPOSED): Xf/Xb = [t][640][32], Xd = [s][784][32]
// hencB: [dir*32+b][t][160] ; hdAll exchange: [s][196][32] (j-major)

// ---------------- ws float layout ----------------
constexpr size_t oXf   = 0;                                // 256 x 640 x 32
constexpr size_t oXb   = oXf   + (size_t)8192*640;
constexpr size_t oXd   = oXb   + (size_t)8192*640;         // 100 x 784 x 32
constexpr size_t oHencB= oXd   + (size_t)3200*784;         // 64 x 256 x 160
constexpr size_t oEncA = oHencB+ (size_t)64*256*160;       // 8192 x 224
constexpr size_t oEs   = oEncA + (size_t)8192*224;         // 3200
constexpr size_t oCT   = oEs   + 3200;                     // 2 x 5120
constexpr size_t oH0   = oCT   + 10240;                    // 32 x 196
constexpr size_t oC0   = oH0   + 6272;                     // 32 x 196
constexpr size_t oHWdsAll = oC0 + 6272;                    // 100 x 32
constexpr size_t oCtxWAll = oHWdsAll + 3200;
constexpr size_t oCopyAll = oCtxWAll + 3200;
constexpr size_t oZidxAll = oCopyAll + 3200;
constexpr size_t oClAll   = oZidxAll + 3200;               // 32
constexpr size_t oNllB    = oClAll + 32;                   // 32
constexpr size_t oW1cT    = oNllB + 32;                    // 320 x 56
constexpr size_t oFEnd    = oW1cT + 17920;
// dec-phase overlays on the (dead) Xf region:
constexpr size_t oHdAll   = 0;                             // 100 x 196 x 32
constexpr size_t oUAll    = oHdAll + (size_t)100*6272;     // 100 x 1792
constexpr size_t oUPreAll = oUAll  + (size_t)100*1792;     // 100 x 1792
constexpr size_t oHwdaAll = oUPreAll + (size_t)100*1792;   // 100 x 32 x 224
constexpr size_t oPartAll = oHwdaAll + (size_t)100*7168;   // 100 x 32 x 224
// ints after floats: in_mapped[8192], cur_ids[3200], flags[...]
#define FENC(d,t,p)  ((((d)*256 + (t))*20 + (p))*16)
#define FLSTM(s,p)   (163840 + ((s)*25 + (p))*16)
constexpr int fEnd = 203840;
constexpr unsigned ENC_FULL  = 0xFFFFFu;

// ---------------- helpers ----------------
__device__ __forceinline__ float fast_tanh(float x){
  float e = __expf(-2.f*fabsf(x));
  float r = (1.f - e) * __builtin_amdgcn_rcpf(1.f + e);
  return copysignf(r, x);
}
__device__ __forceinline__ float sigm(float x){
  return __builtin_amdgcn_rcpf(1.f + __expf(-x));
}
__device__ __forceinline__ float aload(const float* p){
  return __hip_atomic_load(const_cast<float*>(p), __ATOMIC_RELAXED, MSCOPE);
}
__device__ __forceinline__ float2 aload2(const float* p){
  unsigned long long u = __hip_atomic_load(
      reinterpret_cast<unsigned long long*>(const_cast<float*>(p)),
      __ATOMIC_RELAXED, MSCOPE);
  float2 r; __builtin_memcpy(&r, &u, 8); return r;
}
__device__ __forceinline__ void astore(float* p, float v){
  __hip_atomic_store(p, v, __ATOMIC_RELAXED, MSCOPE);
}
__device__ __forceinline__ unsigned uload(unsigned* p){
  return __hip_atomic_load(p, __ATOMIC_RELAXED, MSCOPE);
}
__device__ __forceinline__ void set_line(unsigned* line){
  __hip_atomic_store(line, 1u, __ATOMIC_RELAXED, MSCOPE);
}
template<int SLP>
__device__ __forceinline__ void wait_lines(unsigned* base, int n, int tid){
  if (tid < 64){
    for(;;){
      bool miss = (tid < n) && (uload(base + tid*16) == 0u);
      if (__ballot(miss) == 0ULL) break;
      __builtin_amdgcn_s_sleep(SLP);
    }
  }
  __syncthreads();
}
__device__ __forceinline__ float block_sum(float v, float* red){
  #pragma unroll
  for (int o=32;o;o>>=1) v += __shfl_down(v,o);
  if ((threadIdx.x&63)==0) red[threadIdx.x>>6] = v;
  __syncthreads();
  v = red[0]+red[1]+red[2]+red[3];
  __syncthreads();
  return v;
}

// ---------------- prep: id mapping + flag zeroing ----------------
__global__ void prep_kernel(const int* __restrict__ in_ids, const int* __restrict__ tgt,
                            int* __restrict__ in_mapped, int* __restrict__ cur_ids,
                            unsigned* __restrict__ flags){
  const int g0 = blockIdx.x*256 + threadIdx.x, stride = gridDim.x*256;
  for (int i = g0; i < 8192; i += stride){
    int t = i >> 5, b = i & 31;
    int id = in_ids[b*256 + t];
    in_mapped[i] = (id >= 50000) ? 3 : id;
  }
  for (int i = g0; i < 3200; i += stride){
    int k = i >> 5, b = i & 31;
    int id = (k == 0) ? 1 : tgt[b*100 + (k-1)];
    cur_ids[i] = (id >= 50000) ? 3 : id;
  }
  for (int i = g0; i < fEnd; i += stride) flags[i] = 0u;
}

// ---------------- W1cT[q*56+g] = W1[g][196+q] ----------------
__global__ void w1c_transpose(const float* __restrict__ W1, float* __restrict__ W1cT){
  int i = blockIdx.x*256 + threadIdx.x;
  if (i < 17920){ int q = i / 56, g = i - q*56; W1cT[q*56+g] = W1[(size_t)g*516 + 196 + q]; }
}

// ------- rowgemm: gather emb rows, write TRANSPOSED out[(t*N+g)*32+b] ---------
struct RGArgs{ const int* gid; const float* emb; const float* W;
               const float* bias1; const float* bias2; float* out; int N; };
__global__ void __launch_bounds__(256) rowgemm(RGArgs a){
  __shared__ float rl[8*128];
  const int tid = threadIdx.x;
  const int N = a.N;
  const size_t r0 = (size_t)blockIdx.x*8;
  const size_t t = r0 >> 5; const int b0 = (int)(r0 & 31);
  for (int i = tid; i < 8*128; i += 256){
    int r = i >> 7, k = i & 127;
    rl[i] = a.emb[(size_t)a.gid[r0+r]*128 + k];
  }
  __syncthreads();
  for (int g = tid; g < N; g += 256){
    const float* wr = a.W + (size_t)g*128;
    float acc[8];
    #pragma unroll
    for (int r=0;r<8;r++) acc[r]=0.f;
    for (int k=0;k<128;k+=4){
      float4 wv = *(const float4*)(wr+k);
      #pragma unroll
      for (int r=0;r<8;r++){
        float4 xv = *(const float4*)(rl + r*128 + k);
        acc[r] += wv.x*xv.x + wv.y*xv.y + wv.z*xv.z + wv.w*xv.w;
      }
    }
    float bias = a.bias1[g] + a.bias2[g];
    float* op = a.out + ((size_t)t*N + g)*32 + b0;
    *(float4*)(op)   = make_float4(acc[0]+bias,acc[1]+bias,acc[2]+bias,acc[3]+bias);
    *(float4*)(op+4) = make_float4(acc[4]+bias,acc[5]+bias,acc[6]+bias,acc[7]+bias);
  }
}

// ---------------- es[r] = emb[gid[r]] . Wes ----------------
__global__ void es_kernel(const int* __restrict__ gid, const float* __restrict__ emb,
                          const float* __restrict__ Wes, float* __restrict__ es){
  int r = blockIdx.x, l = threadIdx.x;
  const float* e = emb + (size_t)gid[r]*128;
  float acc = e[l]*Wes[l] + e[l+64]*Wes[l+64];
  #pragma unroll
  for (int o=32;o;o>>=1) acc += __shfl_down(acc,o);
  if (l==0) es[r] = acc;
}

// ---------- encoder bidirectional LSTM (cooperative, 40 WGs, line flags) -------
struct EncArgs{ const float* Xf; const float* Xb; const float* Whf; const float* Whb;
                float* hencB; float* cT; unsigned* flg; };
__global__ void __launch_bounds__(256) enc_scan(EncArgs a){
  extern __shared__ float sm[];
  float* Wl = sm;           // 5120
  float* hl = sm + 5120;    // 32 x 164
  const int wg = blockIdx.x;
  const int dir = wg/20, jwg = wg%20;
  const int tid = threadIdx.x;
  const int b = tid & 31, jl = tid >> 5;
  const int j = jwg*8 + jl;
  const float* Wh = dir ? a.Whb : a.Whf;
  const float* X  = dir ? a.Xb  : a.Xf;
  float* HB = a.hencB + (size_t)dir*32*256*160;
  unsigned* flg = a.flg;
  for (int i = tid; i < 32*160; i += 256){
    int row = i/160, k = i - row*160;
    int gate = row >> 3, jj = row & 7;
    Wl[i] = Wh[((size_t)(gate*160 + jwg*8 + jj))*160 + k];
  }
  for (int i = tid; i < 32*164; i += 256) hl[i] = 0.f;
  float c = 0.f;
  const float4* w0 = (const float4*)(Wl + (0*8+jl)*160);
  const float4* w1 = (const float4*)(Wl + (1*8+jl)*160);
  const float4* w2 = (const float4*)(Wl + (2*8+jl)*160);
  const float4* w3 = (const float4*)(Wl + (3*8+jl)*160);
  __syncthreads();
  for (int t = 0; t < 256; ++t){
    const int trow = dir ? 255 - t : t;
    const float* xr = X + ((size_t)trow*640 + j)*32 + b;
    float g0 = xr[0], g1 = xr[5120], g2 = xr[10240], g3 = xr[15360];
    if (t > 0){
      wait_lines<2>(flg + FENC(dir, t-1, 0), 20, tid);
      const int tprev = dir ? (256 - t) : (t-1);
      for (int i2 = tid; i2 < 2560; i2 += 256){
        int bb = i2/80, kk = (i2 - bb*80)*2;
        float2 v = aload2(HB + ((size_t)bb*256 + tprev)*160 + kk);
        *(float2*)(hl + bb*164 + kk) = v;
      }
    }
    __syncthreads();
    const float4* hr = (const float4*)(hl + b*164);
    #pragma unroll 4
    for (int q = 0; q < 40; ++q){
      float4 hv = hr[q];
      float4 a0 = w0[q], a1 = w1[q], a2 = w2[q], a3 = w3[q];
      g0 += hv.x*a0.x + hv.y*a0.y + hv.z*a0.z + hv.w*a0.w;
      g1 += hv.x*a1.x + hv.y*a1.y + hv.z*a1.z + hv.w*a1.w;
      g2 += hv.x*a2.x + hv.y*a2.y + hv.z*a2.z + hv.w*a2.w;
      g3 += hv.x*a3.x + hv.y*a3.y + hv.z*a3.z + hv.w*a3.w;
    }
    float ig = sigm(g0), fg = sigm(g1), gc = fast_tanh(g2), og = sigm(g3);
    c = fg*c + ig*gc;
    float h = og * fast_tanh(c);
    astore(&HB[((size_t)b*256 + trow)*160 + j], h);
    __syncthreads();
    if (tid == 0) set_line(flg + FENC(dir, t, jwg));
  }
  a.cT[dir*5120 + b*160 + j] = c;
}

// ---------------- mid: h0/c0 projections ----------------
__global__ void mid_kernel(const float* __restrict__ hencB, const float* __restrict__ cT,
                           const float* __restrict__ Weh, const float* __restrict__ beh,
                           const float* __restrict__ Wec, const float* __restrict__ bec,
                           float* __restrict__ h0, float* __restrict__ c0){
  __shared__ float hc[320], cc[320];
  int b = blockIdx.x, tid = threadIdx.x;
  if (tid < 160){
    hc[tid]     = hencB[((size_t)b*256 + 255)*160 + tid];
    hc[160+tid] = hencB[((size_t)(32+b)*256 + 0)*160 + tid];
    cc[tid]     = cT[b*160 + tid];
    cc[160+tid] = cT[5120 + b*160 + tid];
  }
  __syncthreads();
  for (int g = tid; g < 196; g += 256){
    const float* w1 = Weh + (size_t)g*320;
    const float* w2 = Wec + (size_t)g*320;
    float a1 = beh[g], a2 = bec[g];
    for (int k = 0; k < 320; ++k){ a1 += hc[k]*w1[k]; a2 += cc[k]*w2[k]; }
    h0[b*196 + g] = a1;
    c0[b*196 + g] = a2;
  }
}

// ---------------- encA = [hf;hb] @ Wea.T + bea ----------------
__global__ void __launch_bounds__(256) encA_gemm(const float* __restrict__ hencB,
                 const float* __restrict__ Wea, const float* __restrict__ bea,
                 float* __restrict__ encA){
  __shared__ float rl[8*320];
  const int tid = threadIdx.x;
  const size_t r0 = (size_t)blockIdx.x*8;
  for (int i = tid; i < 8*320; i += 256){
    int r = i/320, k = i - r*320;
    size_t row = r0 + r; int b = (int)(row >> 8), t = (int)(row & 255);
    rl[i] = (k < 160) ? hencB[((size_t)b*256 + t)*160 + k]
                      : hencB[((size_t)(32+b)*256 + t)*160 + (k-160)];
  }
  __syncthreads();
  for (int g = tid; g < 224; g += 256){
    const float* wr = Wea + (size_t)g*320;
    float acc[8];
    #pragma unroll
    for (int r=0;r<8;r++) acc[r]=0.f;
    for (int k=0;k<320;k+=4){
      float4 wv = *(const float4*)(wr+k);
      #pragma unroll
      for (int r=0;r<8;r++){
        float4 xv = *(const float4*)(rl + r*320 + k);
        acc[r] += wv.x*xv.x + wv.y*xv.y + wv.z*xv.z + wv.w*xv.w;
      }
    }
    float bias = bea[g];
    #pragma unroll
    for (int r=0;r<8;r++) encA[(r0+r)*224 + g] = acc[r] + bias;
  }
}

// =============== dec_chain: 25 LSTM WGs + 8 aux WGs, ONLY these resident ======
struct ChainArgs{
  const float* Xd; const float* h0; const float* c0;
  const float* Whd; const float* Wda; const float* W1; const float* Wds;
  const float* b1;
  float* hdAll; float* hwdaAll; float* uPreAll; float* hWdsAll;
  unsigned* flg;
};

__device__ __forceinline__ void load_scr(const float* hp, float* scr, int tid){
  for (int i2 = tid; i2 < 3136; i2 += 256){
    float2 hv = aload2(hp + i2*2);
    int e = i2*2; int b2 = e & 31; int j2 = e >> 5;
    scr[b2*204 + j2]     = hv.x;
    scr[(b2+1)*204 + j2] = hv.y;
  }
}

__global__ void __launch_bounds__(256) dec_chain(ChainArgs A){
  extern __shared__ float sm[];
  const int wg = blockIdx.x, tid = threadIdx.x;
  const int bp = tid & 31, jl = tid >> 5;
  unsigned* flg = A.flg;

  if (wg < 25){
    // -------- LSTM chain (25 WGs): gates only, line flags --------
    const int wl = wg;
    const int j = wl*8 + jl;
    float* Wl  = sm;           // 6272
    float* scr = sm + 6272;    // 32 x 204
    for (int i = tid; i < 32*196; i += 256){
      int row = i/196, k = i - row*196;
      int gate = row >> 3, jj = row & 7;
      int jg = wl*8 + jj;
      Wl[i] = (jg < 196) ? A.Whd[((size_t)(gate*196 + jg))*196 + k] : 0.f;
    }
    float c = (j < 196) ? A.c0[bp*196 + j] : 0.f;
    for (int i = tid; i < 6272; i += 256){
      int bb = i/196, k = i - bb*196;
      scr[bb*204 + k] = A.h0[i];
    }
    const float4* w0 = (const float4*)(Wl + (0*8+jl)*196);
    const float4* w1 = (const float4*)(Wl + (1*8+jl)*196);
    const float4* w2 = (const float4*)(Wl + (2*8+jl)*196);
    const float4* w3 = (const float4*)(Wl + (3*8+jl)*196);
    __syncthreads();
    for (int s = 0; s < 100; ++s){
      float x0=0.f,x1=0.f,x2=0.f,x3=0.f;
      if (j < 196){
        const float* xr = A.Xd + ((size_t)s*784 + j)*32 + bp;
        x0 = xr[0]; x1 = xr[6272]; x2 = xr[12544]; x3 = xr[18816];
      }
      if (s > 0){
        wait_lines<2>(flg + FLSTM(s-1, 0), 25, tid);
        load_scr(A.hdAll + (size_t)(s-1)*6272, scr, tid);
      }
      __syncthreads();
      if (j < 196){
        float g0=x0,g1=x1,g2=x2,g3=x3;
        const float4* hr = (const float4*)(scr + bp*204);
        #pragma unroll 7
        for (int q = 0; q < 49; ++q){
          float4 hv = hr[q];
          float4 a0 = w0[q], a1 = w1[q], a2 = w2[q], a3 = w3[q];
          g0 += hv.x*a0.x + hv.y*a0.y + hv.z*a0.z + hv.w*a0.w;
          g1 += hv.x*a1.x + hv.y*a1.y + hv.z*a1.z + hv.w*a1.w;
          g2 += hv.x*a2.x + hv.y*a2.y + hv.z*a2.z + hv.w*a2.w;
          g3 += hv.x*a3.x + hv.y*a3.y + hv.z*a3.z + hv.w*a3.w;
        }
        float ig = sigm(g0), fg = sigm(g1), gc = fast_tanh(g2), og = sigm(g3);
        c = fg*c + ig*gc;
        float h = og * fast_tanh(c);
        astore(&A.hdAll[(size_t)s*6272 + j*32 + bp], h);   // [s][j][b]
      }
      __syncthreads();               // drain: h at LLC
      if (tid == 0) set_line(flg + FLSTM(s, wl));
    }
    return;
  }

  // -------- aux stage (8 WGs): hwda / uPre / hWds; plain stores --------
  {
    const int a_ = wg - 25;
    float* wdaL = sm;            // 28*196
    float* w1hL = sm + 5488;     // 7*196
    float* WdsL = sm + 6860;     // 196
    float* scr  = sm + 7056;     // 6528
    for (int i = tid; i < 28*196; i += 256){
      int al = i/196, k = i - al*196;
      wdaL[i] = A.Wda[(size_t)(a_*28 + al)*196 + k];
    }
    for (int i = tid; i < 7*196; i += 256){
      int gl = i/196, k = i - gl*196;
      w1hL[i] = A.W1[(size_t)(a_*7 + gl)*516 + k];
    }
    if (a_ == 7) for (int i = tid; i < 196; i += 256) WdsL[i] = A.Wds[i];
    __syncthreads();
    for (int s = 0; s < 100; ++s){
      wait_lines<2>(flg + FLSTM(s, 0), 25, tid);
      load_scr(A.hdAll + (size_t)s*6272, scr, tid);
      __syncthreads();
      for (int i = tid; i < 896; i += 256){
        int b2 = i & 31, al = i >> 5;
        const float4* h4 = (const float4*)(scr + b2*204);
        const float4* w4 = (const float4*)(wdaL + al*196);
        float acc = 0.f;
        #pragma unroll 7
        for (int q = 0; q < 49; ++q){
          float4 a4 = h4[q], b4 = w4[q];
          acc += a4.x*b4.x + a4.y*b4.y + a4.z*b4.z + a4.w*b4.w;
        }
        A.hwdaAll[(size_t)s*7168 + b2*224 + a_*28 + al] = acc;
      }
      if (tid < 224){
        int b2 = tid & 31, gl = tid >> 5;
        int g = a_*7 + gl;
        const float4* h4 = (const float4*)(scr + b2*204);
        const float4* w4 = (const float4*)(w1hL + gl*196);
        float acc = A.b1[g];
        #pragma unroll 7
        for (int q = 0; q < 49; ++q){
          float4 a4 = h4[q], b4 = w4[q];
          acc += a4.x*b4.x + a4.y*b4.y + a4.z*b4.z + a4.w*b4.w;
        }
        A.uPreAll[(size_t)s*1792 + b2*56 + g] = acc;
      }
      if (a_ == 7 && tid < 32){
        const float* hb = scr + tid*204;
        float acc = 0.f;
        #pragma unroll 4
        for (int q = 0; q < 196; ++q) acc += hb[q]*WdsL[q];
        A.hWdsAll[s*32 + tid] = acc;
      }
      __syncthreads();
    }
  }
}

// =============== dec_att: 32 WGs, per-batch serial attention, NO waits ========
struct AttArgs{
  const float* hencB; const float* encA;
  const float* Wca; const float* vat; const float* W1cT; const float* Wcs;
  const float* hwdaAll; const float* uPreAll;
  const int* in_ids; const int* tgt;
  float* uAll; float* ctxWAll; float* copyAll; float* clAll;
};

__global__ void __launch_bounds__(256) dec_att(AttArgs A){
  __shared__ float sm[2812];
  const int b = blockIdx.x, tid = threadIdx.x;
  float* hwdaL = sm;           // 224
  float* attnL = sm + 224;     // 256
  float* pctx  = sm + 480;     // 960
  float* ctxL  = sm + 1440;    // 320
  float* red   = sm + 1760;    // 4
  float* pu    = sm + 1764;    // 224
  float* wcaL  = sm + 1988;    // 224
  float* vL    = sm + 2212;    // 224
  float* WcsL  = sm + 2436;    // 320
  if (tid < 224){ wcaL[tid] = A.Wca[tid]; vL[tid] = A.vat[tid]; }
  for (int i = tid; i < 320; i += 256) WcsL[i] = A.Wcs[i];
  const int inid = A.in_ids[b*256 + tid];
  const float4* erow = (const float4*)(A.encA + (size_t)(b*256 + tid)*224);
  float cov = 0.f, clr = 0.f;
  __syncthreads();
  for (int s = 0; s < 100; ++s){
    if (tid < 224) hwdaL[tid] = A.hwdaAll[(size_t)s*7168 + b*224 + tid];
    __syncthreads();
    float exv = 0.f;
    if (inid != 0){
      float acc = 0.f;
      #pragma unroll 8
      for (int q = 0; q < 56; ++q){
        float4 ev = erow[q]; int a0 = 4*q;
        acc += fast_tanh(ev.x + hwdaL[a0]   + cov*wcaL[a0]  )*vL[a0];
        acc += fast_tanh(ev.y + hwdaL[a0+1] + cov*wcaL[a0+1])*vL[a0+1];
        acc += fast_tanh(ev.z + hwdaL[a0+2] + cov*wcaL[a0+2])*vL[a0+2];
        acc += fast_tanh(ev.w + hwdaL[a0+3] + cov*wcaL[a0+3])*vL[a0+3];
      }
      exv = __expf(acc);
    }
    float S = block_sum(exv, red);
    float attn = exv * __builtin_amdgcn_rcpf(S);
    attnL[tid] = attn;
    const int ntb = A.tgt[b*100 + s];
    float cpS = block_sum((inid == ntb) ? attn : 0.f, red);
    float mnS = block_sum(fminf(attn, cov), red);
    if (tid == 0){
      A.copyAll[s*32 + b] = cpS;
      clr += mnS;
      if (s == 99) A.clAll[b] = clr;
    }
    cov += attn;
    if (tid < 240){
      int seg = tid/80, h4i = tid - seg*80;
      int t0 = seg*86, t1 = (t0+86 < 256) ? t0+86 : 256;
      const float* base = (h4i < 40)
        ? (A.hencB + ((size_t)b*256)*160 + (size_t)h4i*4)
        : (A.hencB + ((size_t)(32+b)*256)*160 + (size_t)(h4i-40)*4);
      float4 accv = {0.f,0.f,0.f,0.f};
      #pragma unroll 4
      for (int t2 = t0; t2 < t1; ++t2){
        float av = attnL[t2];
        float4 ev = *(const float4*)(base + (size_t)t2*160);
        accv.x += av*ev.x; accv.y += av*ev.y; accv.z += av*ev.z; accv.w += av*ev.w;
      }
      *(float4*)(pctx + (seg*80+h4i)*4) = accv;
    }
    __syncthreads();
    if (tid < 80){
      float4 p0 = *(float4*)(pctx + tid*4);
      float4 p1 = *(float4*)(pctx + (80+tid)*4);
      float4 p2v = *(float4*)(pctx + (160+tid)*4);
      float4 cvv;
      cvv.x = p0.x+p1.x+p2v.x; cvv.y = p0.y+p1.y+p2v.y;
      cvv.z = p0.z+p1.z+p2v.z; cvv.w = p0.w+p1.w+p2v.w;
      *(float4*)(ctxL + tid*4) = cvv;
    }
    __syncthreads();
    if (tid < 224){
      int g = tid % 56, seg = tid / 56;
      float acc = 0.f;
      const float* wp = A.W1cT + (size_t)seg*80*56 + g;
      #pragma unroll 4
      for (int q = 0; q < 80; ++q) acc += ctxL[seg*80 + q] * wp[q*56];
      pu[seg*56 + g] = acc;
    } else {
      int l = tid - 224; float acc = 0.f;
      for (int q = l; q < 320; q += 32) acc += ctxL[q]*WcsL[q];
      #pragma unroll
      for (int o=16;o;o>>=1) acc += __shfl_down(acc,o,32);
      if (l==0) A.ctxWAll[s*32 + b] = acc;
    }
    __syncthreads();
    if (tid < 56){
      float upre = A.uPreAll[(size_t)s*1792 + b*56 + tid];
      A.uAll[(size_t)s*1792 + b*56 + tid] =
        fast_tanh(upre + pu[tid] + pu[56+tid] + pu[112+tid] + pu[168+tid]);
    }
    __syncthreads();
  }
}

// =============== dec_voc: 224 chunk WGs, W2 pinned, NO waits ==================
struct VocArgs{
  const float* W2; const float* b2; const float* uAll; const int* tgt;
  float* zidxAll; float* partAll;
};

__global__ void __launch_bounds__(256) dec_voc(VocArgs A){
  __shared__ float ulL[1792];
  __shared__ float redW[128];
  __shared__ int idxL[32];
  const int wgv = blockIdx.x, tid = threadIdx.x;
  const int vs = (int)(((long long)wgv*49998)/224);
  const int ve = (int)(((long long)(wgv+1)*49998)/224);
  const int v = vs + tid;
  const bool valid = v < ve;
  const int vc = valid ? v : 0;
  float4 w2r[14];
  {
    const float4* wr = (const float4*)(A.W2 + (size_t)vc*56);
    #pragma unroll
    for (int q=0;q<14;++q) w2r[q] = wr[q];
  }
  const float b2v = A.b2[vc];
  const int lane = tid & 63, wv2 = tid >> 6;
  for (int s = 0; s < 100; ++s){
    for (int i = tid; i < 448; i += 256)
      *(float4*)(ulL + i*4) = *(const float4*)(&A.uAll[(size_t)s*1792 + i*4]);
    if (tid < 32){
      int nt3 = A.tgt[tid*100 + s];
      int ix = nt3 - 2; ix = ix<0?0:(ix>49997?49997:ix);
      idxL[tid] = ix;
    }
    __syncthreads();
    #pragma unroll 4
    for (int bb=0; bb<32; ++bb){
      const float4* uv = (const float4*)(ulL + bb*56);
      float z = b2v;
      #pragma unroll
      for (int q=0;q<14;++q){
        float4 u4 = uv[q];
        z += w2r[q].x*u4.x + w2r[q].y*u4.y + w2r[q].z*u4.z + w2r[q].w*u4.w;
      }
      if (valid && v == idxL[bb]) A.zidxAll[s*32+bb] = z;
      float sv2 = valid ? __expf(z) : 0.f;
      #pragma unroll
      for (int o=32;o;o>>=1) sv2 += __shfl_down(sv2,o);
      if (lane == 0) redW[wv2*32+bb] = sv2;
    }
    __syncthreads();
    if (tid < 32)
      A.partAll[(size_t)(s*32+tid)*224 + wgv] =
        redW[tid]+redW[32+tid]+redW[64+tid]+redW[96+tid];
    __syncthreads();
  }
}

// =============== dec_fin1: 32 WGs -> nllB[b] ==================================
struct Fin1Args{
  const float* partAll; const int* tgt;
  const float* ctxWAll; const float* hWdsAll; const float* es;
  const float* zidxAll; const float* copyAll; const float* bcs;
  float* nllB;
};
__global__ void __launch_bounds__(256) dec_fin1(Fin1Args A){
  __shared__ float red[4];
  const int b = blockIdx.x, tid = threadIdx.x;
  float nll = 0.f;
  const float bcs0 = A.bcs[0];
  for (int s = 0; s < 100; ++s){
    int p = s*32 + b;
    float pv = (tid < 224) ? A.partAll[(size_t)p*224 + tid] : 0.f;
    float se = block_sum(pv, red);
    if (tid == 0){
      int nt2 = A.tgt[b*100 + s];
      float xg = A.ctxWAll[p] + bcs0 + A.hWdsAll[p] + A.es[p];
      float pg = 1.f/(1.f + __expf(-xg));
      float genp = (nt2 >= 2 && nt2 < 50000) ? (__expf(A.zidxAll[p]) / se) : 0.f;
      float pr = pg*genp + (1.f-pg)*A.copyAll[p];
      nll += -logf(pr + 1e-9f);
    }
  }
  if (tid == 0) A.nllB[b] = nll;
}

// =============== dec_fin2: 1 WG -> out[3] =====================================
__global__ void dec_fin2(const float* __restrict__ nllB, const float* __restrict__ clAll,
                         float* __restrict__ out){
  int tid = threadIdx.x;           // 64 threads
  float n = (tid < 32) ? nllB[tid] : 0.f;
  float cv = (tid < 32) ? clAll[tid] : 0.f;
  #pragma unroll
  for (int o=32;o;o>>=1){ n += __shfl_down(n,o); cv += __shfl_down(cv,o); }
  if (tid == 0){ out[0]=n; out[1]=cv; out[2]=n + 0.75f*cv; }
}

// ---------------- host launch ----------------
extern "C" void kernel_launch(void* const* d_in, const int* in_sizes, int n_in,
                              void* d_out, int out_size, void* d_ws, size_t ws_size,
                              hipStream_t stream){
  const int*   in_ids = (const int*)  d_in[0];
  const int*   tgt    = (const int*)  d_in[1];
  const float* emb    = (const float*)d_in[3];
  const float* Wi_f   = (const float*)d_in[4];
  const float* Wh_f   = (const float*)d_in[5];
  const float* bi_f   = (const float*)d_in[6];
  const float* bh_f   = (const float*)d_in[7];
  const float* Wi_b   = (const float*)d_in[8];
  const float* Wh_b   = (const float*)d_in[9];
  const float* bi_b   = (const float*)d_in[10];
  const float* bh_b   = (const float*)d_in[11];
  const float* Weh    = (const float*)d_in[12];
  const float* beh    = (const float*)d_in[13];
  const float* Wec    = (const float*)d_in[14];
  const float* bec    = (const float*)d_in[15];
  const float* Wi_d   = (const float*)d_in[16];
  const float* Wh_d   = (const float*)d_in[17];
  const float* bi_d   = (const float*)d_in[18];
  const float* bh_d   = (const float*)d_in[19];
  const float* Wea    = (const float*)d_in[20];
  const float* bea    = (const float*)d_in[21];
  const float* Wda    = (const float*)d_in[22];
  const float* Wca    = (const float*)d_in[23];
  const float* vat    = (const float*)d_in[24];
  const float* W1     = (const float*)d_in[25];
  const float* b1     = (const float*)d_in[26];
  const float* W2     = (const float*)d_in[27];
  const float* b2     = (const float*)d_in[28];
  const float* Wcs    = (const float*)d_in[29];
  const float* bcs    = (const float*)d_in[30];
  const float* Wds    = (const float*)d_in[31];
  const float* Wes    = (const float*)d_in[32];

  float* ws = (float*)d_ws;
  int* iBase = (int*)(ws + oFEnd);
  int* in_mapped = iBase;
  int* cur_ids   = iBase + 8192;
  unsigned* flags = (unsigned*)(iBase + 11392);

  prep_kernel<<<512, 256, 0, stream>>>(in_ids, tgt, in_mapped, cur_ids, flags);
  w1c_transpose<<<70, 256, 0, stream>>>(W1, ws + oW1cT);

  { RGArgs a{in_mapped, emb, Wi_f, bi_f, bh_f, ws + oXf, 640};
    rowgemm<<<1024, 256, 0, stream>>>(a); }
  { RGArgs a{in_mapped, emb, Wi_b, bi_b, bh_b, ws + oXb, 640};
    rowgemm<<<1024, 256, 0, stream>>>(a); }
  { RGArgs a{cur_ids, emb, Wi_d, bi_d, bh_d, ws + oXd, 784};
    rowgemm<<<400, 256, 0, stream>>>(a); }

  es_kernel<<<3200, 64, 0, stream>>>(cur_ids, emb, Wes, ws + oEs);

  { EncArgs ea{ws + oXf, ws + oXb, Wh_f, Wh_b, ws + oHencB, ws + oCT, flags};
    void* ka[] = {&ea};
    hipLaunchCooperativeKernel((void*)enc_scan, dim3(40), dim3(256), ka,
                               (unsigned)((5120 + 32*164)*4), stream); }

  mid_kernel<<<32, 256, 0, stream>>>(ws + oHencB, ws + oCT, Weh, beh, Wec, bec,
                                     ws + oH0, ws + oC0);

  encA_gemm<<<1024, 256, 0, stream>>>(ws + oHencB, Wea, bea, ws + oEncA);

  { ChainArgs ca{ws + oXd, ws + oH0, ws + oC0,
                 Wh_d, Wda, W1, Wds, b1,
                 ws + oHdAll, ws + oHwdaAll, ws + oUPreAll, ws + oHWdsAll,
                 flags};
    dec_chain<<<dim3(33), dim3(256), 13584*4, stream>>>(ca); }

  { AttArgs aa{ws + oHencB, ws + oEncA,
               Wca, vat, ws + oW1cT, Wcs,
               ws + oHwdaAll, ws + oUPreAll,
               in_ids, tgt,
               ws + oUAll, ws + oCtxWAll, ws + oCopyAll, ws + oClAll};
    dec_att<<<dim3(32), dim3(256), 0, stream>>>(aa); }

  { VocArgs va{W2, b2, ws + oUAll, tgt, ws + oZidxAll, ws + oPartAll};
    dec_voc<<<dim3(224), dim3(256), 0, stream>>>(va); }

  { Fin1Args fa{ws + oPartAll, tgt, ws + oCtxWAll, ws + oHWdsAll, ws + oEs,
                ws + oZidxAll, ws + oCopyAll, bcs, ws + oNllB};
    dec_fin1<<<dim3(32), dim3(256), 0, stream>>>(fa); }

  dec_fin2<<<dim3(1), dim3(64), 0, stream>>>(ws + oNllB, ws + oClAll,
                                             (float*)d_out);
}

// Round 15
// 5083.239 us; speedup vs baseline: 1.2762x; 1.2762x over previous
//
#include <hip/hip_runtime.h>

#define MSCOPE __HIP_MEMORY_SCOPE_AGENT

typedef __attribute__((ext_vector_type(8))) short bf16x8;
typedef __attribute__((ext_vector_type(4))) float f32x4;

// ---------------- model dims ----------------
// V=50000 E=128 H=160 D=196 A=224 BN=56, B=32, Tin=256, Ttgt=100
// X layouts (TRANSPOSED): Xf/Xb = [t][640][32], Xd = [s][784][32]
// hencB: [dir*32+b][t][160]
// MFMA frags: A row=lane&15,k=(lane>>4)*8+e ; C/D col=lane&15(b), row=(lane>>4)*4+i

// ---------------- ws float layout ----------------
constexpr size_t oXf   = 0;                                // 256 x 640 x 32
constexpr size_t oXb   = oXf   + (size_t)8192*640;
constexpr size_t oXd   = oXb   + (size_t)8192*640;         // 100 x 784 x 32
constexpr size_t oHencB= oXd   + (size_t)3200*784;         // 64 x 256 x 160
constexpr size_t oEncA = oHencB+ (size_t)64*256*160;       // 8192 x 224
constexpr size_t oEs   = oEncA + (size_t)8192*224;         // 3200
constexpr size_t oCT   = oEs   + 3200;                     // 2 x 5120
constexpr size_t oH0   = oCT   + 10240;                    // 32 x 196
constexpr size_t oC0   = oH0   + 6272;                     // 32 x 196
constexpr size_t oHWdsAll = oC0 + 6272;                    // 100 x 32
constexpr size_t oCtxWAll = oHWdsAll + 3200;
constexpr size_t oCopyAll = oCtxWAll + 3200;
constexpr size_t oZidxAll = oCopyAll + 3200;
constexpr size_t oClAll   = oZidxAll + 3200;               // 32
constexpr size_t oNllWg   = oClAll + 32;                   // 216
constexpr size_t oW1cT    = oNllWg + 224;                  // 320 x 56
constexpr size_t oAFl     = oW1cT + 17920;                 // 52*7*64 bf16x8 = 93184 f
constexpr size_t oAFa     = oAFl + 93184;                  // 18*7*64 bf16x8 = 32256 f
constexpr size_t oHdF     = oAFa + 32256;                  // 100 x 3584 dwords
constexpr size_t oFEnd    = oHdF + 358400;
// dec-phase overlays on the (dead) Xf region:
constexpr size_t oUAll    = 0;                             // 100 x 1792
constexpr size_t oUPreAll = oUAll  + (size_t)100*1792;     // 100 x 1792
constexpr size_t oHwdaAll = oUPreAll + (size_t)100*1792;   // 100 x 32 x 224
constexpr size_t oPartAll = oHwdaAll + (size_t)100*7168;   // 100 x 32 x 216
// ints after floats: in_mapped[8192], cur_ids[3200], flags[...]
#define FENC(d,t,p)  ((((d)*256 + (t))*40 + (p))*16)
#define FLSTM(s,p)   (327680 + ((s)*8 + (p))*16)
#define FAUX(s,p)    (340480 + ((s)*8 + (p))*16)
#define FP2(s,m,b)   (353280 + (((s)*4 + (m))*32 + (b))*16)
#define CP3          558080
#define CFIN         558096
constexpr int fEnd = 558112;

// ---------------- helpers ----------------
__device__ __forceinline__ float fast_tanh(float x){
  float e = __expf(-2.f*fabsf(x));
  float r = (1.f - e) * __builtin_amdgcn_rcpf(1.f + e);
  return copysignf(r, x);
}
__device__ __forceinline__ float sigm(float x){
  return __builtin_amdgcn_rcpf(1.f + __expf(-x));
}
__device__ __forceinline__ unsigned bfr(float f){      // fp32 -> bf16 (RNE)
  unsigned u = __float_as_uint(f);
  return (u + 0x7FFFu + ((u>>16)&1u)) >> 16;
}
__device__ __forceinline__ float aload(const float* p){
  return __hip_atomic_load(const_cast<float*>(p), __ATOMIC_RELAXED, MSCOPE);
}
__device__ __forceinline__ float2 aload2(const float* p){
  unsigned long long u = __hip_atomic_load(
      reinterpret_cast<unsigned long long*>(const_cast<float*>(p)),
      __ATOMIC_RELAXED, MSCOPE);
  float2 r; __builtin_memcpy(&r, &u, 8); return r;
}
__device__ __forceinline__ void astore(float* p, float v){
  __hip_atomic_store(p, v, __ATOMIC_RELAXED, MSCOPE);
}
__device__ __forceinline__ void astoreu(unsigned* p, unsigned v){
  __hip_atomic_store(p, v, __ATOMIC_RELAXED, MSCOPE);
}
__device__ __forceinline__ void astore2(float* p, float a, float b){
  float2 t; t.x = a; t.y = b;
  unsigned long long u; __builtin_memcpy(&u, &t, 8);
  __hip_atomic_store(reinterpret_cast<unsigned long long*>(p), u,
                     __ATOMIC_RELAXED, MSCOPE);
}
__device__ __forceinline__ unsigned uload(unsigned* p){
  return __hip_atomic_load(p, __ATOMIC_RELAXED, MSCOPE);
}
__device__ __forceinline__ void set_line(unsigned* line){
  __hip_atomic_store(line, 1u, __ATOMIC_RELAXED, MSCOPE);
}
template<int SLP>
__device__ __forceinline__ void wait_lines(unsigned* base, int n, int tid){
  if (tid < 64){
    for(;;){
      bool miss = (tid < n) && (uload(base + tid*16) == 0u);
      if (__ballot(miss) == 0ULL) break;
      __builtin_amdgcn_s_sleep(SLP);
    }
  }
  __syncthreads();
}
__device__ __forceinline__ void add1(unsigned* word){
  (void)__hip_atomic_fetch_add(word, 1u, __ATOMIC_RELAXED, MSCOPE);
}
__device__ __forceinline__ float block_sum(float v, float* red){
  #pragma unroll
  for (int o=32;o;o>>=1) v += __shfl_down(v,o);
  if ((threadIdx.x&63)==0) red[threadIdx.x>>6] = v;
  __syncthreads();
  v = red[0]+red[1]+red[2]+red[3];
  __syncthreads();
  return v;
}

// ---------------- prep: id mapping + flag/hdF zeroing ----------------
__global__ void prep_kernel(const int* __restrict__ in_ids, const int* __restrict__ tgt,
                            int* __restrict__ in_mapped, int* __restrict__ cur_ids,
                            unsigned* __restrict__ flags, float* __restrict__ hdF){
  const int g0 = blockIdx.x*256 + threadIdx.x, stride = gridDim.x*256;
  for (int i = g0; i < 8192; i += stride){
    int t = i >> 5, b = i & 31;
    int id = in_ids[b*256 + t];
    in_mapped[i] = (id >= 50000) ? 3 : id;
  }
  for (int i = g0; i < 3200; i += stride){
    int k = i >> 5, b = i & 31;
    int id = (k == 0) ? 1 : tgt[b*100 + (k-1)];
    cur_ids[i] = (id >= 50000) ? 3 : id;
  }
  for (int i = g0; i < fEnd; i += stride) flags[i] = 0u;
  for (int i = g0; i < 358400; i += stride) hdF[i] = 0.f;
}

// ---------------- W1cT[q*56+g] = W1[g][196+q] ----------------
__global__ void w1c_transpose(const float* __restrict__ W1, float* __restrict__ W1cT){
  int i = blockIdx.x*256 + threadIdx.x;
  if (i < 17920){ int q = i / 56, g = i - q*56; W1cT[q*56+g] = W1[(size_t)g*516 + 196 + q]; }
}

// -------- pack MFMA A-fragments (bf16) for decoder LSTM + aux ----------
__global__ void pack_af(const float* __restrict__ Whd, float* __restrict__ AFl,
                        const float* __restrict__ Wda, const float* __restrict__ W1,
                        const float* __restrict__ Wds, float* __restrict__ AFa){
  int dw = blockIdx.x*256 + threadIdx.x;
  if (dw < 93184){
    int frag = dw>>2, d = dw&3;
    int T = frag/448, r2 = frag - T*448;
    int k7 = r2>>6, l = r2&63;
    int jb = T>>2, gate = T&3;
    int j = jb*16 + (l&15);
    int k0 = k7*32 + ((l>>4)<<3) + 2*d;
    unsigned lo=0, hi=0;
    if (j < 196){
      if (k0   < 196) lo = bfr(Whd[(size_t)(gate*196+j)*196 + k0]);
      if (k0+1 < 196) hi = bfr(Whd[(size_t)(gate*196+j)*196 + k0+1]);
    }
    ((unsigned*)AFl)[dw] = lo | (hi<<16);
  }
  if (dw < 32256){
    int frag = dw>>2, d = dw&3;
    int T = frag/448, r2 = frag - T*448;
    int k7 = r2>>6, l = r2&63;
    int ar = T*16 + (l&15);
    int k0 = k7*32 + ((l>>4)<<3) + 2*d;
    unsigned lo=0, hi=0;
    #pragma unroll
    for (int h = 0; h < 2; ++h){
      int k = k0 + h;
      float v = 0.f;
      if (k < 196){
        if (ar < 224) v = Wda[(size_t)ar*196 + k];
        else { int g = ar - 224;
          if (g < 56) v = W1[(size_t)g*516 + k];
          else if (g == 56) v = Wds[k];
        }
      }
      if (h == 0) lo = bfr(v); else hi = bfr(v);
    }
    ((unsigned*)AFa)[dw] = lo | (hi<<16);
  }
}

// ------- rowgemm: gather emb rows, write TRANSPOSED out[(t*N+g)*32+b] ---------
struct RGArgs{ const int* gid; const float* emb; const float* W;
               const float* bias1; const float* bias2; float* out; int N; };
__global__ void __launch_bounds__(256) rowgemm(RGArgs a){
  __shared__ float rl[8*128];
  const int tid = threadIdx.x;
  const int N = a.N;
  const size_t r0 = (size_t)blockIdx.x*8;
  const size_t t = r0 >> 5; const int b0 = (int)(r0 & 31);
  for (int i = tid; i < 8*128; i += 256){
    int r = i >> 7, k = i & 127;
    rl[i] = a.emb[(size_t)a.gid[r0+r]*128 + k];
  }
  __syncthreads();
  for (int g = tid; g < N; g += 256){
    const float* wr = a.W + (size_t)g*128;
    float acc[8];
    #pragma unroll
    for (int r=0;r<8;r++) acc[r]=0.f;
    for (int k=0;k<128;k+=4){
      float4 wv = *(const float4*)(wr+k);
      #pragma unroll
      for (int r=0;r<8;r++){
        float4 xv = *(const float4*)(rl + r*128 + k);
        acc[r] += wv.x*xv.x + wv.y*xv.y + wv.z*xv.z + wv.w*xv.w;
      }
    }
    float bias = a.bias1[g] + a.bias2[g];
    float* op = a.out + ((size_t)t*N + g)*32 + b0;
    *(float4*)(op)   = make_float4(acc[0]+bias,acc[1]+bias,acc[2]+bias,acc[3]+bias);
    *(float4*)(op+4) = make_float4(acc[4]+bias,acc[5]+bias,acc[6]+bias,acc[7]+bias);
  }
}

// ---------------- es[r] = emb[gid[r]] . Wes ----------------
__global__ void es_kernel(const int* __restrict__ gid, const float* __restrict__ emb,
                          const float* __restrict__ Wes, float* __restrict__ es){
  int r = blockIdx.x, l = threadIdx.x;
  const float* e = emb + (size_t)gid[r]*128;
  float acc = e[l]*Wes[l] + e[l+64]*Wes[l+64];
  #pragma unroll
  for (int o=32;o;o>>=1) acc += __shfl_down(acc,o);
  if (l==0) es[r] = acc;
}

// ---- encoder bidirectional LSTM (REGULAR launch, 80 WGs x 128 thr, 4 j/WG) ----
struct EncArgs{ const float* Xf; const float* Xb; const float* Whf; const float* Whb;
                float* hencB; float* cT; unsigned* flg; };
__global__ void __launch_bounds__(128) enc_scan(EncArgs a){
  extern __shared__ float sm[];
  float* Wl = sm;           // 16 x 160 = 2560
  float* hl = sm + 2560;    // 32 x 164 = 5248
  const int wg = blockIdx.x;
  const int dir = wg/40, jwg = wg%40;
  const int tid = threadIdx.x;
  const int b = tid & 31, jl = tid >> 5;    // jl < 4
  const int j = jwg*4 + jl;
  const float* Wh = dir ? a.Whb : a.Whf;
  const float* X  = dir ? a.Xb  : a.Xf;
  float* HB = a.hencB + (size_t)dir*32*256*160;
  unsigned* flg = a.flg;
  for (int i = tid; i < 16*160; i += 128){
    int row = i/160, k = i - row*160;
    int gate = row >> 2, jj = row & 3;
    Wl[i] = Wh[((size_t)(gate*160 + jwg*4 + jj))*160 + k];
  }
  for (int i = tid; i < 32*164; i += 128) hl[i] = 0.f;
  float c = 0.f;
  const float4* w0 = (const float4*)(Wl + (0*4+jl)*160);
  const float4* w1 = (const float4*)(Wl + (1*4+jl)*160);
  const float4* w2 = (const float4*)(Wl + (2*4+jl)*160);
  const float4* w3 = (const float4*)(Wl + (3*4+jl)*160);
  __syncthreads();
  for (int t = 0; t < 256; ++t){
    const int trow = dir ? 255 - t : t;
    // X layout [t][g*160+j][b]: issue loads BEFORE the flag wait
    const float* xr = X + ((size_t)trow*640 + j)*32 + b;
    float g0 = xr[0], g1 = xr[5120], g2 = xr[10240], g3 = xr[15360];
    if (t > 0){
      wait_lines<2>(flg + FENC(dir, t-1, 0), 40, tid);
      const int tprev = dir ? (256 - t) : (t-1);
      for (int i2 = tid; i2 < 2560; i2 += 128){
        int bb = i2/80, kk = (i2 - bb*80)*2;
        float2 v = aload2(HB + ((size_t)bb*256 + tprev)*160 + kk);
        *(float2*)(hl + bb*164 + kk) = v;
      }
    }
    __syncthreads();
    const float4* hr = (const float4*)(hl + b*164);
    #pragma unroll 4
    for (int q = 0; q < 40; ++q){
      float4 hv = hr[q];
      float4 a0 = w0[q], a1 = w1[q], a2 = w2[q], a3 = w3[q];
      g0 += hv.x*a0.x + hv.y*a0.y + hv.z*a0.z + hv.w*a0.w;
      g1 += hv.x*a1.x + hv.y*a1.y + hv.z*a1.z + hv.w*a1.w;
      g2 += hv.x*a2.x + hv.y*a2.y + hv.z*a2.z + hv.w*a2.w;
      g3 += hv.x*a3.x + hv.y*a3.y + hv.z*a3.z + hv.w*a3.w;
    }
    float ig = sigm(g0), fg = sigm(g1), gc = fast_tanh(g2), og = sigm(g3);
    c = fg*c + ig*gc;
    float h = og * fast_tanh(c);
    astore(&HB[((size_t)b*256 + trow)*160 + j], h);
    __syncthreads();                       // drain vmcnt: h at LLC
    if (tid == 0) set_line(flg + FENC(dir, t, jwg));
  }
  a.cT[dir*5120 + b*160 + j] = c;
}

// ---------------- mid: h0/c0 projections ----------------
__global__ void mid_kernel(const float* __restrict__ hencB, const float* __restrict__ cT,
                           const float* __restrict__ Weh, const float* __restrict__ beh,
                           const float* __restrict__ Wec, const float* __restrict__ bec,
                           float* __restrict__ h0, float* __restrict__ c0){
  __shared__ float hc[320], cc[320];
  int b = blockIdx.x, tid = threadIdx.x;
  if (tid < 160){
    hc[tid]     = hencB[((size_t)b*256 + 255)*160 + tid];
    hc[160+tid] = hencB[((size_t)(32+b)*256 + 0)*160 + tid];
    cc[tid]     = cT[b*160 + tid];
    cc[160+tid] = cT[5120 + b*160 + tid];
  }
  __syncthreads();
  for (int g = tid; g < 196; g += 256){
    const float* w1 = Weh + (size_t)g*320;
    const float* w2 = Wec + (size_t)g*320;
    float a1 = beh[g], a2 = bec[g];
    for (int k = 0; k < 320; ++k){ a1 += hc[k]*w1[k]; a2 += cc[k]*w2[k]; }
    h0[b*196 + g] = a1;
    c0[b*196 + g] = a2;
  }
}

// ---------------- encA = [hf;hb] @ Wea.T + bea ----------------
__global__ void __launch_bounds__(256) encA_gemm(const float* __restrict__ hencB,
                 const float* __restrict__ Wea, const float* __restrict__ bea,
                 float* __restrict__ encA){
  __shared__ float rl[8*320];
  const int tid = threadIdx.x;
  const size_t r0 = (size_t)blockIdx.x*8;
  for (int i = tid; i < 8*320; i += 256){
    int r = i/320, k = i - r*320;
    size_t row = r0 + r; int b = (int)(row >> 8), t = (int)(row & 255);
    rl[i] = (k < 160) ? hencB[((size_t)b*256 + t)*160 + k]
                      : hencB[((size_t)(32+b)*256 + t)*160 + (k-160)];
  }
  __syncthreads();
  for (int g = tid; g < 224; g += 256){
    const float* wr = Wea + (size_t)g*320;
    float acc[8];
    #pragma unroll
    for (int r=0;r<8;r++) acc[r]=0.f;
    for (int k=0;k<320;k+=4){
      float4 wv = *(const float4*)(wr+k);
      #pragma unroll
      for (int r=0;r<8;r++){
        float4 xv = *(const float4*)(rl + r*320 + k);
        acc[r] += wv.x*xv.x + wv.y*xv.y + wv.z*xv.z + wv.w*xv.w;
      }
    }
    float bias = bea[g];
    #pragma unroll
    for (int r=0;r<8;r++) encA[(r0+r)*224 + g] = acc[r] + bias;
  }
}

// ---------------- decoder pipeline (REGULAR launch, grid=256) ----------------
// wg 0-7: L-WGs (MFMA LSTM+aux, LDS-resident weights) | wg 8-39: P2 (b=wg-8)
// wg 40-255: P3 (216 WGs). No grid.sync -> regular launch; flags only.
struct DecArgs{
  const float* Xd; const float* hencB; const float* encA;
  const float* h0; const float* c0; const float* AFl; const float* AFa;
  float* hdF;
  const float* Wca; const float* vat; const float* W1cT; const float* b1;
  const float* W2; const float* b2;
  const float* Wcs; const float* bcs; const float* es;
  const int* in_ids; const int* tgt;
  float* uAll; float* uPreAll; float* hwdaAll;
  float* hWdsAll; float* ctxWAll; float* copyAll;
  float* zidxAll; float* partAll; float* clAll; float* nllWg; float* out;
  unsigned* flg;
};

__global__ void __launch_bounds__(256) dec_scan(DecArgs A){
  extern __shared__ float sm[];
  const int wg = blockIdx.x, tid = threadIdx.x;
  unsigned* flg = A.flg;

  if (wg < 8){
    // ======== L-WG q: MFMA LSTM (its jb-units) + aux tiles, weights in LDS ====
    const int q = wg;
    const int nUq  = (q < 5) ? 2 : 1;
    const int jb0q = q;
    const int jb1q = (q < 5) ? q + 8 : 0;
    const int auxB = (q < 5) ? q : (q == 5 ? 5 : (q == 6 ? 9 : 13));
    const int auxC = (q < 5) ? 1 : (q == 7 ? 5 : 4);
    unsigned* ldsu = (unsigned*)sm;
    bf16x8*   ldsf = (bf16x8*)sm;
    const int AB = nUq*1792;                    // aux slot base (bf16x8 slots)
    const int l = tid & 63, wv = tid >> 6;
    const int lq = l >> 4, lc = l & 15;
    const int u = wv >> 1, nt = wv & 1;
    const bool act = u < nUq;
    const int jb = (u == 0) ? jb0q : jb1q;
    // ---- copy A-frags into LDS (one-time) ----
    {
      const unsigned* aflu = (const unsigned*)A.AFl;
      const unsigned* afau = (const unsigned*)A.AFa;
      const int totDw = (AB + auxC*448)*4;
      for (int i = tid; i < totDw; i += 256){
        int slot = i>>2, d = i&3;
        unsigned v;
        if (slot < AB){
          int uu = slot/1792, r = slot - uu*1792;
          int fi = r>>6, ll = r&63;             // fi = g*7+k7
          int jbu = (uu == 0) ? jb0q : jb1q;
          int T = jbu*4 + fi/7, k7 = fi%7;
          v = aflu[(((size_t)T*7 + k7)*64 + ll)*4 + d];
        } else {
          int r = slot - AB;
          int a = r/448, r2 = r - a*448;
          int k7 = r2>>6, ll = r2&63;
          v = afau[((((size_t)(auxB + a))*7 + k7)*64 + ll)*4 + d];
        }
        ldsu[i] = v;
      }
    }
    // ---- init c-state + B-fragments from h0/c0 ----
    float cst[4];
    if (act){
      int b = nt*16 + lc;
      #pragma unroll
      for (int i = 0; i < 4; ++i){
        int j = jb*16 + lq*4 + i;
        cst[i] = (j < 196) ? A.c0[b*196 + j] : 0.f;
      }
    }
    bf16x8 Bfr[7][2];
    #pragma unroll
    for (int k7 = 0; k7 < 7; ++k7)
      #pragma unroll
      for (int ntt = 0; ntt < 2; ++ntt){
        short tmp[8];
        #pragma unroll
        for (int e = 0; e < 8; ++e){
          int k = k7*32 + lq*8 + e;
          int b = ntt*16 + lc;
          float hv = (k < 196) ? A.h0[b*196 + k] : 0.f;
          tmp[e] = (short)bfr(hv);
        }
        __builtin_memcpy(&Bfr[k7][ntt], tmp, 16);
      }
    __syncthreads();
    unsigned* hdF = (unsigned*)A.hdF;
    for (int s = 0; s < 100; ++s){
      const float* Xs = A.Xd + (size_t)s*25088;
      if (act){
        float xg4[4][4];
        #pragma unroll
        for (int g = 0; g < 4; ++g)
          #pragma unroll
          for (int i = 0; i < 4; ++i){
            int j = jb*16 + lq*4 + i;
            int b = nt*16 + lc;
            xg4[g][i] = (j < 196) ? Xs[((size_t)(g*196 + j))*32 + b] : 0.f;
          }
        f32x4 acc[4];
        #pragma unroll
        for (int g = 0; g < 4; ++g){
          f32x4 a0 = {0.f,0.f,0.f,0.f};
          #pragma unroll
          for (int k7 = 0; k7 < 7; ++k7){
            bf16x8 af = ldsf[(u*28 + g*7 + k7)*64 + l];
            a0 = __builtin_amdgcn_mfma_f32_16x16x32_bf16(af, Bfr[k7][nt], a0, 0,0,0);
          }
          acc[g] = a0;
        }
        float hv4[4];
        #pragma unroll
        for (int i = 0; i < 4; ++i){
          float I = acc[0][i]+xg4[0][i], F = acc[1][i]+xg4[1][i];
          float G = acc[2][i]+xg4[2][i], O = acc[3][i]+xg4[3][i];
          float cc = sigm(F)*cst[i] + sigm(I)*fast_tanh(G);
          cst[i] = cc;
          hv4[i] = sigm(O)*fast_tanh(cc);
        }
        #pragma unroll
        for (int p = 0; p < 2; ++p){
          int jp = jb*16 + lq*4 + 2*p;
          if (jp < 196){
            int k7 = jp>>5, tl = lc | (((jp>>3)&3)<<4), d = (jp&7)>>1;
            unsigned w = bfr(hv4[2*p]) | (bfr(hv4[2*p+1])<<16);
            astoreu(&hdF[(size_t)s*3584 + ((k7*2+nt)*64 + tl)*4 + d], w);
          }
        }
      }
      __syncthreads();               // drain h stores
      if (tid == 0) set_line(flg + FLSTM(s, q));
      wait_lines<1>(flg + FLSTM(s, 0), 8, tid);
      // reload B fragments = h(s)
      {
        const float* hp = (const float*)(hdF + (size_t)s*3584);
        #pragma unroll
        for (int k7 = 0; k7 < 7; ++k7)
          #pragma unroll
          for (int ntt = 0; ntt < 2; ++ntt){
            float2 v0 = aload2(hp + (((k7*2+ntt)*64 + l)*4));
            float2 v1 = aload2(hp + (((k7*2+ntt)*64 + l)*4 + 2));
            unsigned dwv[4];
            __builtin_memcpy(dwv, &v0, 8); __builtin_memcpy(dwv+2, &v1, 8);
            __builtin_memcpy(&Bfr[k7][ntt], dwv, 16);
          }
      }
      // aux MFMA: wave wv handles a = wv, wv+4
      for (int a = wv; a < auxC; a += 4){
        int T = auxB + a;
        #pragma unroll
        for (int ntt = 0; ntt < 2; ++ntt){
          f32x4 acc = {0.f,0.f,0.f,0.f};
          #pragma unroll
          for (int k7 = 0; k7 < 7; ++k7){
            bf16x8 af = ldsf[AB + (a*7 + k7)*64 + l];
            acc = __builtin_amdgcn_mfma_f32_16x16x32_bf16(af, Bfr[k7][ntt], acc, 0,0,0);
          }
          int b = ntt*16 + lc;
          #pragma unroll
          for (int p = 0; p < 2; ++p){
            int ar = T*16 + lq*4 + 2*p;
            float v0 = acc[2*p], v1 = acc[2*p+1];
            if (ar < 224){
              astore2(&A.hwdaAll[(size_t)s*7168 + b*224 + ar], v0, v1);
            } else {
              int g = ar - 224;
              if (g < 56) astore2(&A.uPreAll[(size_t)s*1792 + b*56 + g], v0, v1);
              else if (g == 56) astore(&A.hWdsAll[s*32 + b], v0);
            }
          }
        }
      }
      __syncthreads();               // drain aux stores
      if (tid == 0) set_line(flg + FAUX(s, q));
    }
    return;
  }

  if (wg < 40){
    // ======== P2: attention + ctx + u (32 WGs, b = wg-8) ========
    const int b = wg - 8;
    float* hwdaL = sm;           // 224
    float* attnL = sm + 224;     // 256
    float* pctx  = sm + 480;     // 960
    float* ctxL  = sm + 1440;    // 320
    float* red   = sm + 1760;    // 4
    float* pu    = sm + 1764;    // 224
    float* wcaL  = sm + 1988;    // 224
    float* vL    = sm + 2212;    // 224
    float* WcsL  = sm + 2436;    // 320
    float* b1L   = sm + 2756;    // 56
    if (tid < 224){ wcaL[tid] = A.Wca[tid]; vL[tid] = A.vat[tid]; }
    for (int i = tid; i < 320; i += 256) WcsL[i] = A.Wcs[i];
    if (tid < 56) b1L[tid] = A.b1[tid];
    const int inid = A.in_ids[b*256 + tid];
    const float4* erow = (const float4*)(A.encA + (size_t)(b*256 + tid)*224);
    float cov = 0.f, clr = 0.f;
    __syncthreads();
    for (int s = 0; s < 100; ++s){
      wait_lines<2>(flg + FAUX(s, 0), 8, tid);
      if (tid < 224) hwdaL[tid] = aload(&A.hwdaAll[(size_t)s*7168 + b*224 + tid]);
      __syncthreads();
      float exv = 0.f;
      if (inid != 0){
        float acc = 0.f;
        #pragma unroll 8
        for (int q = 0; q < 56; ++q){
          float4 ev = erow[q]; int a0 = 4*q;
          acc += fast_tanh(ev.x + hwdaL[a0]   + cov*wcaL[a0]  )*vL[a0];
          acc += fast_tanh(ev.y + hwdaL[a0+1] + cov*wcaL[a0+1])*vL[a0+1];
          acc += fast_tanh(ev.z + hwdaL[a0+2] + cov*wcaL[a0+2])*vL[a0+2];
          acc += fast_tanh(ev.w + hwdaL[a0+3] + cov*wcaL[a0+3])*vL[a0+3];
        }
        exv = __expf(acc);
      }
      float S = block_sum(exv, red);
      float attn = exv * __builtin_amdgcn_rcpf(S);
      attnL[tid] = attn;
      const int ntb = A.tgt[b*100 + s];
      float cpS = block_sum((inid == ntb) ? attn : 0.f, red);
      float mnS = block_sum(fminf(attn, cov), red);
      if (tid == 0){
        astore(&A.copyAll[s*32 + b], cpS);
        clr += mnS;
        if (s == 99) astore(&A.clAll[b], clr);
      }
      cov += attn;
      if (tid < 240){
        int seg = tid/80, h4i = tid - seg*80;
        int t0 = seg*86, t1 = (t0+86 < 256) ? t0+86 : 256;
        const float* base = (h4i < 40)
          ? (A.hencB + ((size_t)b*256)*160 + (size_t)h4i*4)
          : (A.hencB + ((size_t)(32+b)*256)*160 + (size_t)(h4i-40)*4);
        float4 accv = {0.f,0.f,0.f,0.f};
        #pragma unroll 4
        for (int t2 = t0; t2 < t1; ++t2){
          float av = attnL[t2];
          float4 ev = *(const float4*)(base + (size_t)t2*160);
          accv.x += av*ev.x; accv.y += av*ev.y; accv.z += av*ev.z; accv.w += av*ev.w;
        }
        *(float4*)(pctx + (seg*80+h4i)*4) = accv;
      }
      __syncthreads();
      if (tid < 80){
        float4 p0 = *(float4*)(pctx + tid*4);
        float4 p1 = *(float4*)(pctx + (80+tid)*4);
        float4 p2v = *(float4*)(pctx + (160+tid)*4);
        float4 cvv;
        cvv.x = p0.x+p1.x+p2v.x; cvv.y = p0.y+p1.y+p2v.y;
        cvv.z = p0.z+p1.z+p2v.z; cvv.w = p0.w+p1.w+p2v.w;
        *(float4*)(ctxL + tid*4) = cvv;
      }
      __syncthreads();
      if (tid < 224){
        int g = tid % 56, seg = tid / 56;
        float acc = 0.f;
        const float* wp = A.W1cT + (size_t)seg*80*56 + g;
        #pragma unroll 4
        for (int q = 0; q < 80; ++q) acc += ctxL[seg*80 + q] * wp[q*56];
        pu[seg*56 + g] = acc;
      } else {
        int l = tid - 224; float acc = 0.f;
        for (int q = l; q < 320; q += 32) acc += ctxL[q]*WcsL[q];
        #pragma unroll
        for (int o=16;o;o>>=1) acc += __shfl_down(acc,o,32);
        if (l==0) astore(&A.ctxWAll[s*32 + b], acc);
      }
      __syncthreads();
      if (tid < 56){
        float upre = aload(&A.uPreAll[(size_t)s*1792 + b*56 + tid]);
        float uu = fast_tanh(upre + b1L[tid] + pu[tid] + pu[56+tid] + pu[112+tid] + pu[168+tid]);
        astore(&A.uAll[(size_t)s*1792 + b*56 + tid], uu);
      }
      __syncthreads();
      if (tid == 0){
        set_line(flg + FP2(s,0,b));
        set_line(flg + FP2(s,1,b));
        set_line(flg + FP2(s,2,b));
        set_line(flg + FP2(s,3,b));
      }
    }
    return;
  }

  // ======== P3: vocab sum-exp, W2 rows pinned in registers (216 WGs) ========
  {
    const int wgv = wg - 40;
    const int vs = (int)(((long long)wgv*49998)/216);
    const int ve = (int)(((long long)(wgv+1)*49998)/216);
    const int v = vs + tid;
    const bool valid = v < ve;
    const int vc = valid ? v : 0;
    float4 w2r[14];
    {
      const float4* wr = (const float4*)(A.W2 + (size_t)vc*56);
      #pragma unroll
      for (int q=0;q<14;++q) w2r[q] = wr[q];
    }
    const float b2v = A.b2[vc];
    float* ulL  = sm;                  // 1792
    float* redW = sm + 1792;           // 128
    int*   idxL = (int*)(sm + 1920);   // 32
    float* red  = sm + 1952;           // 4
    const int lane = tid & 63, wv2 = tid >> 6;
    for (int s = 0; s < 100; ++s){
      int nt3 = (tid < 32) ? A.tgt[tid*100 + s] : 0;
      wait_lines<8>(flg + FP2(s, wgv & 3, 0), 32, tid);
      for (int i2 = tid; i2 < 896; i2 += 256){
        float2 u2 = aload2(&A.uAll[(size_t)s*1792 + i2*2]);
        *(float2*)(ulL + i2*2) = u2;
      }
      if (tid < 32){
        int ix = nt3 - 2; ix = ix<0?0:(ix>49997?49997:ix);
        idxL[tid] = ix;
      }
      __syncthreads();
      #pragma unroll 4
      for (int bb=0; bb<32; ++bb){
        const float4* uv = (const float4*)(ulL + bb*56);
        float z = b2v;
        #pragma unroll
        for (int q=0;q<14;++q){
          float4 u4 = uv[q];
          z += w2r[q].x*u4.x + w2r[q].y*u4.y + w2r[q].z*u4.z + w2r[q].w*u4.w;
        }
        if (valid && v == idxL[bb]) astore(&A.zidxAll[s*32+bb], z);
        float sv2 = valid ? __expf(z) : 0.f;
        #pragma unroll
        for (int o=32;o;o>>=1) sv2 += __shfl_down(sv2,o);
        if (lane == 0) redW[wv2*32+bb] = sv2;
      }
      __syncthreads();
      if (tid < 32){
        float tot = redW[tid]+redW[32+tid]+redW[64+tid]+redW[96+tid];
        astore(&A.partAll[(size_t)(s*32+tid)*216 + wgv], tot);
      }
      __syncthreads();
    }
    __syncthreads();
    if (tid == 0) add1(flg + CP3);
    if (tid == 0){
      while (uload(flg + CP3) != 216u) __builtin_amdgcn_s_sleep(32);
    }
    __syncthreads();
    float nll1 = 0.f;
    for (int p = wgv; p < 3200; p += 216){
      float pv = (tid < 216) ? aload(&A.partAll[(size_t)p*216 + tid]) : 0.f;
      float se = block_sum(pv, red);
      if (tid == 0){
        int s = p >> 5, b = p & 31;
        int nt2 = A.tgt[b*100 + s];
        float xg = aload(&A.ctxWAll[p]) + A.bcs[0] + aload(&A.hWdsAll[p]) + A.es[p];
        float pg = 1.f/(1.f + __expf(-xg));
        float genp = (nt2 >= 2 && nt2 < 50000) ? (__expf(aload(&A.zidxAll[p])) / se) : 0.f;
        float pr = pg*genp + (1.f-pg)*aload(&A.copyAll[p]);
        nll1 += -logf(pr + 1e-9f);
      }
    }
    if (tid == 0) astore(&A.nllWg[wgv], nll1);
    __syncthreads();
    if (tid == 0) add1(flg + CFIN);
    if (wg == 40){
      if (tid == 0){
        while (uload(flg + CFIN) != 216u) __builtin_amdgcn_s_sleep(32);
      }
      __syncthreads();
      float nv = (tid < 216) ? aload(&A.nllWg[tid]) : 0.f;
      float nll = block_sum(nv, red);
      float cv = (tid < 32) ? aload(&A.clAll[tid]) : 0.f;
      float cl = block_sum(cv, red);
      if (tid == 0){ A.out[0]=nll; A.out[1]=cl; A.out[2]=nll + 0.75f*cl; }
    }
  }
}

// ---------------- host launch ----------------
extern "C" void kernel_launch(void* const* d_in, const int* in_sizes, int n_in,
                              void* d_out, int out_size, void* d_ws, size_t ws_size,
                              hipStream_t stream){
  const int*   in_ids = (const int*)  d_in[0];
  const int*   tgt    = (const int*)  d_in[1];
  const float* emb    = (const float*)d_in[3];
  const float* Wi_f   = (const float*)d_in[4];
  const float* Wh_f   = (const float*)d_in[5];
  const float* bi_f   = (const float*)d_in[6];
  const float* bh_f   = (const float*)d_in[7];
  const float* Wi_b   = (const float*)d_in[8];
  const float* Wh_b   = (const float*)d_in[9];
  const float* bi_b   = (const float*)d_in[10];
  const float* bh_b   = (const float*)d_in[11];
  const float* Weh    = (const float*)d_in[12];
  const float* beh    = (const float*)d_in[13];
  const float* Wec    = (const float*)d_in[14];
  const float* bec    = (const float*)d_in[15];
  const float* Wi_d   = (const float*)d_in[16];
  const float* Wh_d   = (const float*)d_in[17];
  const float* bi_d   = (const float*)d_in[18];
  const float* bh_d   = (const float*)d_in[19];
  const float* Wea    = (const float*)d_in[20];
  const float* bea    = (const float*)d_in[21];
  const float* Wda    = (const float*)d_in[22];
  const float* Wca    = (const float*)d_in[23];
  const float* vat    = (const float*)d_in[24];
  const float* W1     = (const float*)d_in[25];
  const float* b1     = (const float*)d_in[26];
  const float* W2     = (const float*)d_in[27];
  const float* b2     = (const float*)d_in[28];
  const float* Wcs    = (const float*)d_in[29];
  const float* bcs    = (const float*)d_in[30];
  const float* Wds    = (const float*)d_in[31];
  const float* Wes    = (const float*)d_in[32];

  float* ws = (float*)d_ws;
  int* iBase = (int*)(ws + oFEnd);
  int* in_mapped = iBase;
  int* cur_ids   = iBase + 8192;
  unsigned* flags = (unsigned*)(iBase + 11392);

  prep_kernel<<<512, 256, 0, stream>>>(in_ids, tgt, in_mapped, cur_ids, flags,
                                       ws + oHdF);
  w1c_transpose<<<70, 256, 0, stream>>>(W1, ws + oW1cT);
  pack_af<<<364, 256, 0, stream>>>(Wh_d, ws + oAFl, Wda, W1, Wds, ws + oAFa);

  { RGArgs a{in_mapped, emb, Wi_f, bi_f, bh_f, ws + oXf, 640};
    rowgemm<<<1024, 256, 0, stream>>>(a); }
  { RGArgs a{in_mapped, emb, Wi_b, bi_b, bh_b, ws + oXb, 640};
    rowgemm<<<1024, 256, 0, stream>>>(a); }
  { RGArgs a{cur_ids, emb, Wi_d, bi_d, bh_d, ws + oXd, 784};
    rowgemm<<<400, 256, 0, stream>>>(a); }

  es_kernel<<<3200, 64, 0, stream>>>(cur_ids, emb, Wes, ws + oEs);

  { EncArgs ea{ws + oXf, ws + oXb, Wh_f, Wh_b, ws + oHencB, ws + oCT, flags};
    // Regular launch: enc_scan has no grid.sync; flags provide all ordering.
    enc_scan<<<dim3(80), dim3(128), (2560 + 32*164)*4, stream>>>(ea); }

  mid_kernel<<<32, 256, 0, stream>>>(ws + oHencB, ws + oCT, Weh, beh, Wec, bec,
                                     ws + oH0, ws + oC0);

  encA_gemm<<<1024, 256, 0, stream>>>(ws + oHencB, Wea, bea, ws + oEncA);

  { DecArgs da{ws + oXd, ws + oHencB, ws + oEncA,
               ws + oH0, ws + oC0, ws + oAFl, ws + oAFa,
               ws + oHdF,
               Wca, vat, ws + oW1cT, b1, W2, b2, Wcs, bcs, ws + oEs,
               in_ids, tgt,
               ws + oUAll, ws + oUPreAll, ws + oHwdaAll,
               ws + oHWdsAll, ws + oCtxWAll, ws + oCopyAll,
               ws + oZidxAll, ws + oPartAll, ws + oClAll, ws + oNllWg, (float*)d_out,
               flags};
    dec_scan<<<dim3(256), dim3(256), 64512, stream>>>(da); }
}

// Round 16
// 4865.659 us; speedup vs baseline: 1.3332x; 1.0447x over previous
//
#include <hip/hip_runtime.h>

#define MSCOPE __HIP_MEMORY_SCOPE_AGENT

typedef __attribute__((ext_vector_type(8))) short bf16x8;
typedef __attribute__((ext_vector_type(4))) float f32x4;

// ---------------- model dims ----------------
// V=50000 E=128 H=160 D=196 A=224 BN=56, B=32, Tin=256, Ttgt=100
// X layouts (TRANSPOSED): Xf/Xb = [t][640][32], Xd = [s][784][32]
// hencB: [dir*32+b][t][160]
// MFMA frags: A row=lane&15,k=(lane>>4)*8+e ; C/D col=lane&15(b), row=(lane>>4)*4+i

// ---------------- ws float layout ----------------
constexpr size_t oXf   = 0;                                // 256 x 640 x 32
constexpr size_t oXb   = oXf   + (size_t)8192*640;
constexpr size_t oXd   = oXb   + (size_t)8192*640;         // 100 x 784 x 32
constexpr size_t oHencB= oXd   + (size_t)3200*784;         // 64 x 256 x 160
constexpr size_t oEncA = oHencB+ (size_t)64*256*160;       // 8192 x 224
constexpr size_t oEs   = oEncA + (size_t)8192*224;         // 3200
constexpr size_t oCT   = oEs   + 3200;                     // 2 x 5120
constexpr size_t oH0   = oCT   + 10240;                    // 32 x 196
constexpr size_t oC0   = oH0   + 6272;                     // 32 x 196
constexpr size_t oHWdsAll = oC0 + 6272;                    // 100 x 32
constexpr size_t oCtxWAll = oHWdsAll + 3200;
constexpr size_t oCopyAll = oCtxWAll + 3200;
constexpr size_t oZidxAll = oCopyAll + 3200;
constexpr size_t oClAll   = oZidxAll + 3200;               // 32
constexpr size_t oNllWg   = oClAll + 32;                   // 216
constexpr size_t oW1cT    = oNllWg + 224;                  // 320 x 56
constexpr size_t oAFl     = oW1cT + 17920;                 // 52*7*64 bf16x8 = 93184 f
constexpr size_t oAFa     = oAFl + 93184;                  // 18*7*64 bf16x8 = 32256 f
constexpr size_t oHdF     = oAFa + 32256;                  // 100 x 3584 dwords
constexpr size_t oFEnd    = oHdF + 358400;
// dec-phase overlays on the (dead) Xf region:
constexpr size_t oUAll    = 0;                             // 100 x 1792
constexpr size_t oUPreAll = oUAll  + (size_t)100*1792;     // 100 x 1792
constexpr size_t oHwdaAll = oUPreAll + (size_t)100*1792;   // 100 x 32 x 224
constexpr size_t oPartAll = oHwdaAll + (size_t)100*7168;   // 100 x 32 x 216
// ints after floats: in_mapped[8192], cur_ids[3200], flags[...]
#define FENC(d,t,p)  ((((d)*256 + (t))*20 + (p))*16)
#define FLSTM(s,p)   (163840 + ((s)*8 + (p))*16)
#define FAUX(s,p)    (176640 + ((s)*8 + (p))*16)
#define FP2(s,m,b)   (189440 + (((s)*4 + (m))*32 + (b))*16)
#define CP3          394240
#define CFIN         394256
#define CENC         394272
constexpr int fEnd = 394288;
constexpr unsigned ENC_FULL  = 0xFFFFFu;

// ---------------- helpers ----------------
__device__ __forceinline__ float fast_tanh(float x){
  float e = __expf(-2.f*fabsf(x));
  float r = (1.f - e) * __builtin_amdgcn_rcpf(1.f + e);
  return copysignf(r, x);
}
__device__ __forceinline__ float sigm(float x){
  return __builtin_amdgcn_rcpf(1.f + __expf(-x));
}
__device__ __forceinline__ unsigned bfr(float f){      // fp32 -> bf16 (RNE)
  unsigned u = __float_as_uint(f);
  return (u + 0x7FFFu + ((u>>16)&1u)) >> 16;
}
__device__ __forceinline__ float aload(const float* p){
  return __hip_atomic_load(const_cast<float*>(p), __ATOMIC_RELAXED, MSCOPE);
}
__device__ __forceinline__ float2 aload2(const float* p){
  unsigned long long u = __hip_atomic_load(
      reinterpret_cast<unsigned long long*>(const_cast<float*>(p)),
      __ATOMIC_RELAXED, MSCOPE);
  float2 r; __builtin_memcpy(&r, &u, 8); return r;
}
__device__ __forceinline__ void astore(float* p, float v){
  __hip_atomic_store(p, v, __ATOMIC_RELAXED, MSCOPE);
}
__device__ __forceinline__ void astoreu(unsigned* p, unsigned v){
  __hip_atomic_store(p, v, __ATOMIC_RELAXED, MSCOPE);
}
__device__ __forceinline__ void astore2(float* p, float a, float b){
  float2 t; t.x = a; t.y = b;
  unsigned long long u; __builtin_memcpy(&u, &t, 8);
  __hip_atomic_store(reinterpret_cast<unsigned long long*>(p), u,
                     __ATOMIC_RELAXED, MSCOPE);
}
__device__ __forceinline__ unsigned uload(unsigned* p){
  return __hip_atomic_load(p, __ATOMIC_RELAXED, MSCOPE);
}
__device__ __forceinline__ void set_line(unsigned* line){
  __hip_atomic_store(line, 1u, __ATOMIC_RELAXED, MSCOPE);
}
template<int SLP>
__device__ __forceinline__ void wait_lines(unsigned* base, int n, int tid){
  if (tid < 64){
    for(;;){
      bool miss = (tid < n) && (uload(base + tid*16) == 0u);
      if (__ballot(miss) == 0ULL) break;
      __builtin_amdgcn_s_sleep(SLP);
    }
  }
  __syncthreads();
}
__device__ __forceinline__ void add1(unsigned* word){
  (void)__hip_atomic_fetch_add(word, 1u, __ATOMIC_RELAXED, MSCOPE);
}
__device__ __forceinline__ float block_sum(float v, float* red){
  #pragma unroll
  for (int o=32;o;o>>=1) v += __shfl_down(v,o);
  if ((threadIdx.x&63)==0) red[threadIdx.x>>6] = v;
  __syncthreads();
  v = red[0]+red[1]+red[2]+red[3];
  __syncthreads();
  return v;
}

// ---------------- prep: id mapping + flag/hdF zeroing ----------------
__global__ void prep_kernel(const int* __restrict__ in_ids, const int* __restrict__ tgt,
                            int* __restrict__ in_mapped, int* __restrict__ cur_ids,
                            unsigned* __restrict__ flags, float* __restrict__ hdF){
  const int g0 = blockIdx.x*256 + threadIdx.x, stride = gridDim.x*256;
  for (int i = g0; i < 8192; i += stride){
    int t = i >> 5, b = i & 31;
    int id = in_ids[b*256 + t];
    in_mapped[i] = (id >= 50000) ? 3 : id;
  }
  for (int i = g0; i < 3200; i += stride){
    int k = i >> 5, b = i & 31;
    int id = (k == 0) ? 1 : tgt[b*100 + (k-1)];
    cur_ids[i] = (id >= 50000) ? 3 : id;
  }
  for (int i = g0; i < fEnd; i += stride) flags[i] = 0u;
  for (int i = g0; i < 358400; i += stride) hdF[i] = 0.f;
}

// ------- rowgemm: gather emb rows, write TRANSPOSED out[(t*N+g)*32+b] ---------
struct RGArgs{ const int* gid; const float* emb; const float* W;
               const float* bias1; const float* bias2; float* out; int N; };
__global__ void __launch_bounds__(256) rowgemm(RGArgs a){
  __shared__ float rl[8*128];
  const int tid = threadIdx.x;
  const int N = a.N;
  const size_t r0 = (size_t)blockIdx.x*8;
  const size_t t = r0 >> 5; const int b0 = (int)(r0 & 31);
  for (int i = tid; i < 8*128; i += 256){
    int r = i >> 7, k = i & 127;
    rl[i] = a.emb[(size_t)a.gid[r0+r]*128 + k];
  }
  __syncthreads();
  for (int g = tid; g < N; g += 256){
    const float* wr = a.W + (size_t)g*128;
    float acc[8];
    #pragma unroll
    for (int r=0;r<8;r++) acc[r]=0.f;
    for (int k=0;k<128;k+=4){
      float4 wv = *(const float4*)(wr+k);
      #pragma unroll
      for (int r=0;r<8;r++){
        float4 xv = *(const float4*)(rl + r*128 + k);
        acc[r] += wv.x*xv.x + wv.y*xv.y + wv.z*xv.z + wv.w*xv.w;
      }
    }
    float bias = a.bias1[g] + a.bias2[g];
    float* op = a.out + ((size_t)t*N + g)*32 + b0;
    *(float4*)(op)   = make_float4(acc[0]+bias,acc[1]+bias,acc[2]+bias,acc[3]+bias);
    *(float4*)(op+4) = make_float4(acc[4]+bias,acc[5]+bias,acc[6]+bias,acc[7]+bias);
  }
}

// ====== enc_mega: blocks 0-39 encoder | 40-439 Xd-rowgemm | 440-803 pack_af
//        | 804-873 W1cT | 874-1673 es.  All extras independent of enc chain. ===
struct MegaArgs{
  const float* Xf; const float* Xb; const float* Whf; const float* Whb;
  float* hencB; float* cT; unsigned* flg;
  const int* cur_ids; const float* emb;
  const float* Wi_d; const float* bi_d; const float* bh_d; float* Xd;
  const float* Whd; float* AFl;
  const float* Wda; const float* W1; const float* Wds; float* AFa;
  float* W1cT;
  const float* Wes; float* es;
};

__global__ void __launch_bounds__(256) enc_mega(MegaArgs a){
  extern __shared__ float sm[];
  const int blk = blockIdx.x, tid = threadIdx.x;

  if (blk < 40){
    // ---------------- encoder chain (R13-exact) ----------------
    float* Wl = sm;           // 5120
    float* hl = sm + 5120;    // 32 x 164
    const int dir = blk/20, jwg = blk%20;
    const int b = tid & 31, jl = tid >> 5;
    const int j = jwg*8 + jl;
    const float* Wh = dir ? a.Whb : a.Whf;
    const float* X  = dir ? a.Xb  : a.Xf;
    float* HB = a.hencB + (size_t)dir*32*256*160;
    unsigned* flg = a.flg;
    for (int i = tid; i < 32*160; i += 256){
      int row = i/160, k = i - row*160;
      int gate = row >> 3, jj = row & 7;
      Wl[i] = Wh[((size_t)(gate*160 + jwg*8 + jj))*160 + k];
    }
    for (int i = tid; i < 32*164; i += 256) hl[i] = 0.f;
    float c = 0.f;
    const float4* w0 = (const float4*)(Wl + (0*8+jl)*160);
    const float4* w1 = (const float4*)(Wl + (1*8+jl)*160);
    const float4* w2 = (const float4*)(Wl + (2*8+jl)*160);
    const float4* w3 = (const float4*)(Wl + (3*8+jl)*160);
    __syncthreads();
    for (int t = 0; t < 256; ++t){
      const int trow = dir ? 255 - t : t;
      const float* xr = X + ((size_t)trow*640 + j)*32 + b;
      float g0 = xr[0], g1 = xr[5120], g2 = xr[10240], g3 = xr[15360];
      if (t > 0){
        wait_lines<2>(flg + FENC(dir, t-1, 0), 20, tid);
        const int tprev = dir ? (256 - t) : (t-1);
        for (int i2 = tid; i2 < 2560; i2 += 256){
          int bb = i2/80, kk = (i2 - bb*80)*2;
          float2 v = aload2(HB + ((size_t)bb*256 + tprev)*160 + kk);
          *(float2*)(hl + bb*164 + kk) = v;
        }
      }
      __syncthreads();
      const float4* hr = (const float4*)(hl + b*164);
      #pragma unroll 4
      for (int q = 0; q < 40; ++q){
        float4 hv = hr[q];
        float4 a0 = w0[q], a1 = w1[q], a2 = w2[q], a3 = w3[q];
        g0 += hv.x*a0.x + hv.y*a0.y + hv.z*a0.z + hv.w*a0.w;
        g1 += hv.x*a1.x + hv.y*a1.y + hv.z*a1.z + hv.w*a1.w;
        g2 += hv.x*a2.x + hv.y*a2.y + hv.z*a2.z + hv.w*a2.w;
        g3 += hv.x*a3.x + hv.y*a3.y + hv.z*a3.z + hv.w*a3.w;
      }
      float ig = sigm(g0), fg = sigm(g1), gc = fast_tanh(g2), og = sigm(g3);
      c = fg*c + ig*gc;
      float h = og * fast_tanh(c);
      astore(&HB[((size_t)b*256 + trow)*160 + j], h);
      __syncthreads();
      if (tid == 0) set_line(flg + FENC(dir, t, jwg));
    }
    a.cT[dir*5120 + b*160 + j] = c;
    return;
  }

  if (blk < 440){
    // ---------------- Xd rowgemm (N=784) ----------------
    float* rl = sm;   // 8 x 128
    const size_t r0 = (size_t)(blk - 40)*8;
    const size_t t = r0 >> 5; const int b0 = (int)(r0 & 31);
    for (int i = tid; i < 8*128; i += 256){
      int r = i >> 7, k = i & 127;
      rl[i] = a.emb[(size_t)a.cur_ids[r0+r]*128 + k];
    }
    __syncthreads();
    for (int g = tid; g < 784; g += 256){
      const float* wr = a.Wi_d + (size_t)g*128;
      float acc[8];
      #pragma unroll
      for (int r=0;r<8;r++) acc[r]=0.f;
      for (int k=0;k<128;k+=4){
        float4 wv = *(const float4*)(wr+k);
        #pragma unroll
        for (int r=0;r<8;r++){
          float4 xv = *(const float4*)(rl + r*128 + k);
          acc[r] += wv.x*xv.x + wv.y*xv.y + wv.z*xv.z + wv.w*xv.w;
        }
      }
      float bias = a.bi_d[g] + a.bh_d[g];
      float* op = a.Xd + ((size_t)t*784 + g)*32 + b0;
      *(float4*)(op)   = make_float4(acc[0]+bias,acc[1]+bias,acc[2]+bias,acc[3]+bias);
      *(float4*)(op+4) = make_float4(acc[4]+bias,acc[5]+bias,acc[6]+bias,acc[7]+bias);
    }
    return;
  }

  if (blk < 804){
    // ---------------- pack_af ----------------
    int dw = (blk - 440)*256 + tid;
    if (dw < 93184){
      int frag = dw>>2, d = dw&3;
      int T = frag/448, r2 = frag - T*448;
      int k7 = r2>>6, l = r2&63;
      int jb = T>>2, gate = T&3;
      int j = jb*16 + (l&15);
      int k0 = k7*32 + ((l>>4)<<3) + 2*d;
      unsigned lo=0, hi=0;
      if (j < 196){
        if (k0   < 196) lo = bfr(a.Whd[(size_t)(gate*196+j)*196 + k0]);
        if (k0+1 < 196) hi = bfr(a.Whd[(size_t)(gate*196+j)*196 + k0+1]);
      }
      ((unsigned*)a.AFl)[dw] = lo | (hi<<16);
    }
    if (dw < 32256){
      int frag = dw>>2, d = dw&3;
      int T = frag/448, r2 = frag - T*448;
      int k7 = r2>>6, l = r2&63;
      int ar = T*16 + (l&15);
      int k0 = k7*32 + ((l>>4)<<3) + 2*d;
      unsigned lo=0, hi=0;
      #pragma unroll
      for (int h = 0; h < 2; ++h){
        int k = k0 + h;
        float v = 0.f;
        if (k < 196){
          if (ar < 224) v = a.Wda[(size_t)ar*196 + k];
          else { int g = ar - 224;
            if (g < 56) v = a.W1[(size_t)g*516 + k];
            else if (g == 56) v = a.Wds[k];
          }
        }
        if (h == 0) lo = bfr(v); else hi = bfr(v);
      }
      ((unsigned*)a.AFa)[dw] = lo | (hi<<16);
    }
    return;
  }

  if (blk < 874){
    // ---------------- W1cT ----------------
    int i = (blk - 804)*256 + tid;
    if (i < 17920){ int q = i / 56, g = i - q*56; a.W1cT[q*56+g] = a.W1[(size_t)g*516 + 196 + q]; }
    return;
  }

  // ---------------- es: 4 rows per block ----------------
  {
    int r = (blk - 874)*4 + (tid >> 6);
    int l = tid & 63;
    if (r < 3200){
      const float* e = a.emb + (size_t)a.cur_ids[r]*128;
      float acc = e[l]*a.Wes[l] + e[l+64]*a.Wes[l+64];
      #pragma unroll
      for (int o=32;o;o>>=1) acc += __shfl_down(acc,o);
      if (l==0) a.es[r] = acc;
    }
  }
}

// ---------------- mid: h0/c0 projections ----------------
__global__ void mid_kernel(const float* __restrict__ hencB, const float* __restrict__ cT,
                           const float* __restrict__ Weh, const float* __restrict__ beh,
                           const float* __restrict__ Wec, const float* __restrict__ bec,
                           float* __restrict__ h0, float* __restrict__ c0){
  __shared__ float hc[320], cc[320];
  int b = blockIdx.x, tid = threadIdx.x;
  if (tid < 160){
    hc[tid]     = hencB[((size_t)b*256 + 255)*160 + tid];
    hc[160+tid] = hencB[((size_t)(32+b)*256 + 0)*160 + tid];
    cc[tid]     = cT[b*160 + tid];
    cc[160+tid] = cT[5120 + b*160 + tid];
  }
  __syncthreads();
  for (int g = tid; g < 196; g += 256){
    const float* w1 = Weh + (size_t)g*320;
    const float* w2 = Wec + (size_t)g*320;
    float a1 = beh[g], a2 = bec[g];
    for (int k = 0; k < 320; ++k){ a1 += hc[k]*w1[k]; a2 += cc[k]*w2[k]; }
    h0[b*196 + g] = a1;
    c0[b*196 + g] = a2;
  }
}

// ---------------- decoder pipeline (REGULAR launch, grid=256) ----------------
// wg 0-7: L-WGs (MFMA LSTM+aux) | wg 8-39: P2 (b=wg-8) | wg 40-255: P3 (216)
struct DecArgs{
  const float* Xd; const float* hencB; float* encA;
  const float* h0; const float* c0; const float* AFl; const float* AFa;
  float* hdF;
  const float* Wea; const float* bea;
  const float* Wca; const float* vat; const float* W1cT; const float* b1;
  const float* W2; const float* b2;
  const float* Wcs; const float* bcs; const float* es;
  const int* in_ids; const int* tgt;
  float* uAll; float* uPreAll; float* hwdaAll;
  float* hWdsAll; float* ctxWAll; float* copyAll;
  float* zidxAll; float* partAll; float* clAll; float* nllWg; float* out;
  unsigned* flg;
};

__global__ void __launch_bounds__(256) dec_scan(DecArgs A){
  extern __shared__ float sm[];
  const int wg = blockIdx.x, tid = threadIdx.x;
  unsigned* flg = A.flg;

  if (wg < 8){
    // ======== L-WG q: MFMA LSTM (its jb-units) + aux tiles, weights in LDS ====
    const int q = wg;
    const int nUq  = (q < 5) ? 2 : 1;
    const int jb0q = q;
    const int jb1q = (q < 5) ? q + 8 : 0;
    const int auxB = (q < 5) ? q : (q == 5 ? 5 : (q == 6 ? 9 : 13));
    const int auxC = (q < 5) ? 1 : (q == 7 ? 5 : 4);
    unsigned* ldsu = (unsigned*)sm;
    bf16x8*   ldsf = (bf16x8*)sm;
    const int AB = nUq*1792;                    // aux slot base (bf16x8 slots)
    const int l = tid & 63, wv = tid >> 6;
    const int lq = l >> 4, lc = l & 15;
    const int u = wv >> 1, nt = wv & 1;
    const bool act = u < nUq;
    const int jb = (u == 0) ? jb0q : jb1q;
    // ---- copy A-frags into LDS (one-time) ----
    {
      const unsigned* aflu = (const unsigned*)A.AFl;
      const unsigned* afau = (const unsigned*)A.AFa;
      const int totDw = (AB + auxC*448)*4;
      for (int i = tid; i < totDw; i += 256){
        int slot = i>>2, d = i&3;
        unsigned v;
        if (slot < AB){
          int uu = slot/1792, r = slot - uu*1792;
          int fi = r>>6, ll = r&63;             // fi = g*7+k7
          int jbu = (uu == 0) ? jb0q : jb1q;
          int T = jbu*4 + fi/7, k7 = fi%7;
          v = aflu[(((size_t)T*7 + k7)*64 + ll)*4 + d];
        } else {
          int r = slot - AB;
          int a = r/448, r2 = r - a*448;
          int k7 = r2>>6, ll = r2&63;
          v = afau[((((size_t)(auxB + a))*7 + k7)*64 + ll)*4 + d];
        }
        ldsu[i] = v;
      }
    }
    // ---- init c-state + B-fragments from h0/c0 ----
    float cst[4];
    if (act){
      int b = nt*16 + lc;
      #pragma unroll
      for (int i = 0; i < 4; ++i){
        int j = jb*16 + lq*4 + i;
        cst[i] = (j < 196) ? A.c0[b*196 + j] : 0.f;
      }
    }
    bf16x8 Bfr[7][2];
    #pragma unroll
    for (int k7 = 0; k7 < 7; ++k7)
      #pragma unroll
      for (int ntt = 0; ntt < 2; ++ntt){
        short tmp[8];
        #pragma unroll
        for (int e = 0; e < 8; ++e){
          int k = k7*32 + lq*8 + e;
          int b = ntt*16 + lc;
          float hv = (k < 196) ? A.h0[b*196 + k] : 0.f;
          tmp[e] = (short)bfr(hv);
        }
        __builtin_memcpy(&Bfr[k7][ntt], tmp, 16);
      }
    __syncthreads();
    unsigned* hdF = (unsigned*)A.hdF;
    for (int s = 0; s < 100; ++s){
      const float* Xs = A.Xd + (size_t)s*25088;
      if (act){
        float xg4[4][4];
        #pragma unroll
        for (int g = 0; g < 4; ++g)
          #pragma unroll
          for (int i = 0; i < 4; ++i){
            int j = jb*16 + lq*4 + i;
            int b = nt*16 + lc;
            xg4[g][i] = (j < 196) ? Xs[((size_t)(g*196 + j))*32 + b] : 0.f;
          }
        f32x4 acc[4];
        #pragma unroll
        for (int g = 0; g < 4; ++g){
          f32x4 a0 = {0.f,0.f,0.f,0.f};
          #pragma unroll
          for (int k7 = 0; k7 < 7; ++k7){
            bf16x8 af = ldsf[(u*28 + g*7 + k7)*64 + l];
            a0 = __builtin_amdgcn_mfma_f32_16x16x32_bf16(af, Bfr[k7][nt], a0, 0,0,0);
          }
          acc[g] = a0;
        }
        float hv4[4];
        #pragma unroll
        for (int i = 0; i < 4; ++i){
          float I = acc[0][i]+xg4[0][i], F = acc[1][i]+xg4[1][i];
          float G = acc[2][i]+xg4[2][i], O = acc[3][i]+xg4[3][i];
          float cc = sigm(F)*cst[i] + sigm(I)*fast_tanh(G);
          cst[i] = cc;
          hv4[i] = sigm(O)*fast_tanh(cc);
        }
        #pragma unroll
        for (int p = 0; p < 2; ++p){
          int jp = jb*16 + lq*4 + 2*p;
          if (jp < 196){
            int k7 = jp>>5, tl = lc | (((jp>>3)&3)<<4), d = (jp&7)>>1;
            unsigned w = bfr(hv4[2*p]) | (bfr(hv4[2*p+1])<<16);
            astoreu(&hdF[(size_t)s*3584 + ((k7*2+nt)*64 + tl)*4 + d], w);
          }
        }
      }
      __syncthreads();               // drain h stores
      if (tid == 0) set_line(flg + FLSTM(s, q));
      wait_lines<1>(flg + FLSTM(s, 0), 8, tid);
      // reload B fragments = h(s)
      {
        const float* hp = (const float*)(hdF + (size_t)s*3584);
        #pragma unroll
        for (int k7 = 0; k7 < 7; ++k7)
          #pragma unroll
          for (int ntt = 0; ntt < 2; ++ntt){
            float2 v0 = aload2(hp + (((k7*2+ntt)*64 + l)*4));
            float2 v1 = aload2(hp + (((k7*2+ntt)*64 + l)*4 + 2));
            unsigned dwv[4];
            __builtin_memcpy(dwv, &v0, 8); __builtin_memcpy(dwv+2, &v1, 8);
            __builtin_memcpy(&Bfr[k7][ntt], dwv, 16);
          }
      }
      // aux MFMA: wave wv handles a = wv, wv+4
      for (int a = wv; a < auxC; a += 4){
        int T = auxB + a;
        #pragma unroll
        for (int ntt = 0; ntt < 2; ++ntt){
          f32x4 acc = {0.f,0.f,0.f,0.f};
          #pragma unroll
          for (int k7 = 0; k7 < 7; ++k7){
            bf16x8 af = ldsf[AB + (a*7 + k7)*64 + l];
            acc = __builtin_amdgcn_mfma_f32_16x16x32_bf16(af, Bfr[k7][ntt], acc, 0,0,0);
          }
          int b = ntt*16 + lc;
          #pragma unroll
          for (int p = 0; p < 2; ++p){
            int ar = T*16 + lq*4 + 2*p;
            float v0 = acc[2*p], v1 = acc[2*p+1];
            if (ar < 224){
              astore2(&A.hwdaAll[(size_t)s*7168 + b*224 + ar], v0, v1);
            } else {
              int g = ar - 224;
              if (g < 56) astore2(&A.uPreAll[(size_t)s*1792 + b*56 + g], v0, v1);
              else if (g == 56) astore(&A.hWdsAll[s*32 + b], v0);
            }
          }
        }
      }
      __syncthreads();               // drain aux stores
      if (tid == 0) set_line(flg + FAUX(s, q));
    }
    return;
  }

  if (wg < 40){
    // ======== P2: attention + ctx + u (32 WGs, b = wg-8) ========
    const int b = wg - 8;
    float* hwdaL = sm;           // 224
    float* attnL = sm + 224;     // 256
    float* pctx  = sm + 480;     // 960
    float* ctxL  = sm + 1440;    // 320
    float* red   = sm + 1760;    // 4
    float* pu    = sm + 1764;    // 224
    float* wcaL  = sm + 1988;    // 224
    float* vL    = sm + 2212;    // 224
    float* WcsL  = sm + 2436;    // 320
    float* b1L   = sm + 2756;    // 56
    if (tid < 224){ wcaL[tid] = A.Wca[tid]; vL[tid] = A.vat[tid]; }
    for (int i = tid; i < 320; i += 256) WcsL[i] = A.Wcs[i];
    if (tid < 56) b1L[tid] = A.b1[tid];
    const int inid = A.in_ids[b*256 + tid];
    const float4* erow = (const float4*)(A.encA + (size_t)(b*256 + tid)*224);
    float cov = 0.f, clr = 0.f;
    // wait for in-kernel encA (P3 prologue) to complete
    if (tid == 0){
      while (uload(flg + CENC) != 216u) __builtin_amdgcn_s_sleep(8);
    }
    __syncthreads();
    for (int s = 0; s < 100; ++s){
      wait_lines<2>(flg + FAUX(s, 0), 8, tid);
      if (tid < 224) hwdaL[tid] = aload(&A.hwdaAll[(size_t)s*7168 + b*224 + tid]);
      __syncthreads();
      float exv = 0.f;
      if (inid != 0){
        float acc = 0.f;
        #pragma unroll 8
        for (int q = 0; q < 56; ++q){
          float4 ev = erow[q]; int a0 = 4*q;
          acc += fast_tanh(ev.x + hwdaL[a0]   + cov*wcaL[a0]  )*vL[a0];
          acc += fast_tanh(ev.y + hwdaL[a0+1] + cov*wcaL[a0+1])*vL[a0+1];
          acc += fast_tanh(ev.z + hwdaL[a0+2] + cov*wcaL[a0+2])*vL[a0+2];
          acc += fast_tanh(ev.w + hwdaL[a0+3] + cov*wcaL[a0+3])*vL[a0+3];
        }
        exv = __expf(acc);
      }
      float S = block_sum(exv, red);
      float attn = exv * __builtin_amdgcn_rcpf(S);
      attnL[tid] = attn;
      const int ntb = A.tgt[b*100 + s];
      float cpS = block_sum((inid == ntb) ? attn : 0.f, red);
      float mnS = block_sum(fminf(attn, cov), red);
      if (tid == 0){
        astore(&A.copyAll[s*32 + b], cpS);
        clr += mnS;
        if (s == 99) astore(&A.clAll[b], clr);
      }
      cov += attn;
      if (tid < 240){
        int seg = tid/80, h4i = tid - seg*80;
        int t0 = seg*86, t1 = (t0+86 < 256) ? t0+86 : 256;
        const float* base = (h4i < 40)
          ? (A.hencB + ((size_t)b*256)*160 + (size_t)h4i*4)
          : (A.hencB + ((size_t)(32+b)*256)*160 + (size_t)(h4i-40)*4);
        float4 accv = {0.f,0.f,0.f,0.f};
        #pragma unroll 4
        for (int t2 = t0; t2 < t1; ++t2){
          float av = attnL[t2];
          float4 ev = *(const float4*)(base + (size_t)t2*160);
          accv.x += av*ev.x; accv.y += av*ev.y; accv.z += av*ev.z; accv.w += av*ev.w;
        }
        *(float4*)(pctx + (seg*80+h4i)*4) = accv;
      }
      __syncthreads();
      if (tid < 80){
        float4 p0 = *(float4*)(pctx + tid*4);
        float4 p1 = *(float4*)(pctx + (80+tid)*4);
        float4 p2v = *(float4*)(pctx + (160+tid)*4);
        float4 cvv;
        cvv.x = p0.x+p1.x+p2v.x; cvv.y = p0.y+p1.y+p2v.y;
        cvv.z = p0.z+p1.z+p2v.z; cvv.w = p0.w+p1.w+p2v.w;
        *(float4*)(ctxL + tid*4) = cvv;
      }
      __syncthreads();
      if (tid < 224){
        int g = tid % 56, seg = tid / 56;
        float acc = 0.f;
        const float* wp = A.W1cT + (size_t)seg*80*56 + g;
        #pragma unroll 4
        for (int q = 0; q < 80; ++q) acc += ctxL[seg*80 + q] * wp[q*56];
        pu[seg*56 + g] = acc;
      } else {
        int l = tid - 224; float acc = 0.f;
        for (int q = l; q < 320; q += 32) acc += ctxL[q]*WcsL[q];
        #pragma unroll
        for (int o=16;o;o>>=1) acc += __shfl_down(acc,o,32);
        if (l==0) astore(&A.ctxWAll[s*32 + b], acc);
      }
      __syncthreads();
      if (tid < 56){
        float upre = aload(&A.uPreAll[(size_t)s*1792 + b*56 + tid]);
        float uu = fast_tanh(upre + b1L[tid] + pu[tid] + pu[56+tid] + pu[112+tid] + pu[168+tid]);
        astore(&A.uAll[(size_t)s*1792 + b*56 + tid], uu);
      }
      __syncthreads();
      if (tid == 0){
        set_line(flg + FP2(s,0,b));
        set_line(flg + FP2(s,1,b));
        set_line(flg + FP2(s,2,b));
        set_line(flg + FP2(s,3,b));
      }
    }
    return;
  }

  // ======== P3: encA prologue, then vocab sum-exp (216 WGs) ========
  {
    const int wgv = wg - 40;
    // ---- encA prologue: rows [wgv*38, wgv*38+38) of encA = [hf;hb]@Wea.T+bea
    {
      float* hlrow = sm;   // 320 floats
      for (int rr = 0; rr < 38; ++rr){
        int row = wgv*38 + rr;
        if (row < 8192){
          int b = row >> 8, t = row & 255;
          for (int k = tid; k < 320; k += 256)
            hlrow[k] = (k < 160) ? A.hencB[((size_t)b*256 + t)*160 + k]
                                 : A.hencB[((size_t)(32+b)*256 + t)*160 + (k-160)];
          __syncthreads();
          if (tid < 224){
            const float* wr = A.Wea + (size_t)tid*320;
            float acc = A.bea[tid];
            for (int k = 0; k < 320; k += 4){
              float4 wv = *(const float4*)(wr+k);
              float4 xv = *(const float4*)(hlrow+k);
              acc += wv.x*xv.x + wv.y*xv.y + wv.z*xv.z + wv.w*xv.w;
            }
            astore(&A.encA[(size_t)row*224 + tid], acc);
          }
          __syncthreads();
        }
      }
      __syncthreads();             // drain encA stores to LLC
      if (tid == 0) add1(flg + CENC);
    }
    const int vs = (int)(((long long)wgv*49998)/216);
    const int ve = (int)(((long long)(wgv+1)*49998)/216);
    const int v = vs + tid;
    const bool valid = v < ve;
    const int vc = valid ? v : 0;
    float4 w2r[14];
    {
      const float4* wr = (const float4*)(A.W2 + (size_t)vc*56);
      #pragma unroll
      for (int q=0;q<14;++q) w2r[q] = wr[q];
    }
    const float b2v = A.b2[vc];
    float* ulL  = sm;                  // 1792
    float* redW = sm + 1792;           // 128
    int*   idxL = (int*)(sm + 1920);   // 32
    float* red  = sm + 1952;           // 4
    const int lane = tid & 63, wv2 = tid >> 6;
    for (int s = 0; s < 100; ++s){
      int nt3 = (tid < 32) ? A.tgt[tid*100 + s] : 0;
      wait_lines<8>(flg + FP2(s, wgv & 3, 0), 32, tid);
      for (int i2 = tid; i2 < 896; i2 += 256){
        float2 u2 = aload2(&A.uAll[(size_t)s*1792 + i2*2]);
        *(float2*)(ulL + i2*2) = u2;
      }
      if (tid < 32){
        int ix = nt3 - 2; ix = ix<0?0:(ix>49997?49997:ix);
        idxL[tid] = ix;
      }
      __syncthreads();
      #pragma unroll 4
      for (int bb=0; bb<32; ++bb){
        const float4* uv = (const float4*)(ulL + bb*56);
        float z = b2v;
        #pragma unroll
        for (int q=0;q<14;++q){
          float4 u4 = uv[q];
          z += w2r[q].x*u4.x + w2r[q].y*u4.y + w2r[q].z*u4.z + w2r[q].w*u4.w;
        }
        if (valid && v == idxL[bb]) astore(&A.zidxAll[s*32+bb], z);
        float sv2 = valid ? __expf(z) : 0.f;
        #pragma unroll
        for (int o=32;o;o>>=1) sv2 += __shfl_down(sv2,o);
        if (lane == 0) redW[wv2*32+bb] = sv2;
      }
      __syncthreads();
      if (tid < 32){
        float tot = redW[tid]+redW[32+tid]+redW[64+tid]+redW[96+tid];
        astore(&A.partAll[(size_t)(s*32+tid)*216 + wgv], tot);
      }
      __syncthreads();
    }
    __syncthreads();
    if (tid == 0) add1(flg + CP3);
    if (tid == 0){
      while (uload(flg + CP3) != 216u) __builtin_amdgcn_s_sleep(32);
    }
    __syncthreads();
    float nll1 = 0.f;
    for (int p = wgv; p < 3200; p += 216){
      float pv = (tid < 216) ? aload(&A.partAll[(size_t)p*216 + tid]) : 0.f;
      float se = block_sum(pv, red);
      if (tid == 0){
        int s = p >> 5, b = p & 31;
        int nt2 = A.tgt[b*100 + s];
        float xg = aload(&A.ctxWAll[p]) + A.bcs[0] + aload(&A.hWdsAll[p]) + A.es[p];
        float pg = 1.f/(1.f + __expf(-xg));
        float genp = (nt2 >= 2 && nt2 < 50000) ? (__expf(aload(&A.zidxAll[p])) / se) : 0.f;
        float pr = pg*genp + (1.f-pg)*aload(&A.copyAll[p]);
        nll1 += -logf(pr + 1e-9f);
      }
    }
    if (tid == 0) astore(&A.nllWg[wgv], nll1);
    __syncthreads();
    if (tid == 0) add1(flg + CFIN);
    if (wg == 40){
      if (tid == 0){
        while (uload(flg + CFIN) != 216u) __builtin_amdgcn_s_sleep(32);
      }
      __syncthreads();
      float nv = (tid < 216) ? aload(&A.nllWg[tid]) : 0.f;
      float nll = block_sum(nv, red);
      float cv = (tid < 32) ? aload(&A.clAll[tid]) : 0.f;
      float cl = block_sum(cv, red);
      if (tid == 0){ A.out[0]=nll; A.out[1]=cl; A.out[2]=nll + 0.75f*cl; }
    }
  }
}

// ---------------- host launch ----------------
extern "C" void kernel_launch(void* const* d_in, const int* in_sizes, int n_in,
                              void* d_out, int out_size, void* d_ws, size_t ws_size,
                              hipStream_t stream){
  const int*   in_ids = (const int*)  d_in[0];
  const int*   tgt    = (const int*)  d_in[1];
  const float* emb    = (const float*)d_in[3];
  const float* Wi_f   = (const float*)d_in[4];
  const float* Wh_f   = (const float*)d_in[5];
  const float* bi_f   = (const float*)d_in[6];
  const float* bh_f   = (const float*)d_in[7];
  const float* Wi_b   = (const float*)d_in[8];
  const float* Wh_b   = (const float*)d_in[9];
  const float* bi_b   = (const float*)d_in[10];
  const float* bh_b   = (const float*)d_in[11];
  const float* Weh    = (const float*)d_in[12];
  const float* beh    = (const float*)d_in[13];
  const float* Wec    = (const float*)d_in[14];
  const float* bec    = (const float*)d_in[15];
  const float* Wi_d   = (const float*)d_in[16];
  const float* Wh_d   = (const float*)d_in[17];
  const float* bi_d   = (const float*)d_in[18];
  const float* bh_d   = (const float*)d_in[19];
  const float* Wea    = (const float*)d_in[20];
  const float* bea    = (const float*)d_in[21];
  const float* Wda    = (const float*)d_in[22];
  const float* Wca    = (const float*)d_in[23];
  const float* vat    = (const float*)d_in[24];
  const float* W1     = (const float*)d_in[25];
  const float* b1     = (const float*)d_in[26];
  const float* W2     = (const float*)d_in[27];
  const float* b2     = (const float*)d_in[28];
  const float* Wcs    = (const float*)d_in[29];
  const float* bcs    = (const float*)d_in[30];
  const float* Wds    = (const float*)d_in[31];
  const float* Wes    = (const float*)d_in[32];

  float* ws = (float*)d_ws;
  int* iBase = (int*)(ws + oFEnd);
  int* in_mapped = iBase;
  int* cur_ids   = iBase + 8192;
  unsigned* flags = (unsigned*)(iBase + 11392);

  prep_kernel<<<512, 256, 0, stream>>>(in_ids, tgt, in_mapped, cur_ids, flags,
                                       ws + oHdF);

  { RGArgs a{in_mapped, emb, Wi_f, bi_f, bh_f, ws + oXf, 640};
    rowgemm<<<1024, 256, 0, stream>>>(a); }
  { RGArgs a{in_mapped, emb, Wi_b, bi_b, bh_b, ws + oXb, 640};
    rowgemm<<<1024, 256, 0, stream>>>(a); }

  { MegaArgs ma{ws + oXf, ws + oXb, Wh_f, Wh_b, ws + oHencB, ws + oCT, flags,
                cur_ids, emb, Wi_d, bi_d, bh_d, ws + oXd,
                Wh_d, ws + oAFl, Wda, W1, Wds, ws + oAFa,
                ws + oW1cT, Wes, ws + oEs};
    enc_mega<<<dim3(1674), dim3(256), (5120 + 32*164)*4, stream>>>(ma); }

  mid_kernel<<<32, 256, 0, stream>>>(ws + oHencB, ws + oCT, Weh, beh, Wec, bec,
                                     ws + oH0, ws + oC0);

  { DecArgs da{ws + oXd, ws + oHencB, ws + oEncA,
               ws + oH0, ws + oC0, ws + oAFl, ws + oAFa,
               ws + oHdF,
               Wea, bea,
               Wca, vat, ws + oW1cT, b1, W2, b2, Wcs, bcs, ws + oEs,
               in_ids, tgt,
               ws + oUAll, ws + oUPreAll, ws + oHwdaAll,
               ws + oHWdsAll, ws + oCtxWAll, ws + oCopyAll,
               ws + oZidxAll, ws + oPartAll, ws + oClAll, ws + oNllWg, (float*)d_out,
               flags};
    dec_scan<<<dim3(256), dim3(256), 64512, stream>>>(da); }
}

// Round 17
// 4565.480 us; speedup vs baseline: 1.4209x; 1.0657x over previous
//
#include <hip/hip_runtime.h>

#define MSCOPE __HIP_MEMORY_SCOPE_AGENT

typedef __attribute__((ext_vector_type(8))) short bf16x8;
typedef __attribute__((ext_vector_type(4))) float f32x4;

// ---------------- model dims ----------------
// V=50000 E=128 H=160 D=196 A=224 BN=56, B=32, Tin=256, Ttgt=100
// X layouts (TRANSPOSED): Xf/Xb = [t][640][32], Xd = [s][784][32]
// hencB: [dir*32+b][t][160]
// MFMA frags: A row=lane&15,k=(lane>>4)*8+e ; C/D col=lane&15(b), row=(lane>>4)*4+i

// ---------------- ws float layout ----------------
constexpr size_t oXf   = 0;                                // 256 x 640 x 32
constexpr size_t oXb   = oXf   + (size_t)8192*640;
constexpr size_t oXd   = oXb   + (size_t)8192*640;         // 100 x 784 x 32
constexpr size_t oHencB= oXd   + (size_t)3200*784;         // 64 x 256 x 160
constexpr size_t oEncA = oHencB+ (size_t)64*256*160;       // 8192 x 224
constexpr size_t oEs   = oEncA + (size_t)8192*224;         // 3200
constexpr size_t oCT   = oEs   + 3200;                     // 2 x 5120
constexpr size_t oH0   = oCT   + 10240;                    // 32 x 196
constexpr size_t oC0   = oH0   + 6272;                     // 32 x 196
constexpr size_t oHWdsAll = oC0 + 6272;                    // 100 x 32
constexpr size_t oCtxWAll = oHWdsAll + 3200;
constexpr size_t oCopyAll = oCtxWAll + 3200;
constexpr size_t oZidxAll = oCopyAll + 3200;
constexpr size_t oClAll   = oZidxAll + 3200;               // 32
constexpr size_t oNllWg   = oClAll + 32;                   // 216
constexpr size_t oW1cT    = oNllWg + 224;                  // 320 x 56
constexpr size_t oAFl     = oW1cT + 17920;                 // 52*7*64 bf16x8 = 93184 f
constexpr size_t oAFa     = oAFl + 93184;                  // 18*7*64 bf16x8 = 32256 f
constexpr size_t oHdF     = oAFa + 32256;                  // 100 x 3584 dwords
constexpr size_t oFEnd    = oHdF + 358400;
// dec-phase overlays on the (dead) Xf region:
constexpr size_t oUAll    = 0;                             // 100 x 1792
constexpr size_t oUPreAll = oUAll  + (size_t)100*1792;     // 100 x 1792
constexpr size_t oHwdaAll = oUPreAll + (size_t)100*1792;   // 100 x 32 x 224
constexpr size_t oPartAll = oHwdaAll + (size_t)100*7168;   // 100 x 32 x 216
// ints after floats: in_mapped[8192], cur_ids[3200], flags[...]
#define FENC(d,t,p)  ((((d)*256 + (t))*20 + (p))*16)
#define FLSTM(s,p)   (163840 + ((s)*8 + (p))*16)
#define FAUX(s,p)    (176640 + ((s)*8 + (p))*16)
#define FP2(s,m,b)   (189440 + (((s)*4 + (m))*32 + (b))*16)
#define CP3          394240
#define CFIN         394256
constexpr int fEnd = 394272;
constexpr unsigned ENC_FULL  = 0xFFFFFu;

// ---------------- helpers ----------------
__device__ __forceinline__ float fast_tanh(float x){
  float e = __expf(-2.f*fabsf(x));
  float r = (1.f - e) * __builtin_amdgcn_rcpf(1.f + e);
  return copysignf(r, x);
}
__device__ __forceinline__ float sigm(float x){
  return __builtin_amdgcn_rcpf(1.f + __expf(-x));
}
__device__ __forceinline__ unsigned bfr(float f){      // fp32 -> bf16 (RNE)
  unsigned u = __float_as_uint(f);
  return (u + 0x7FFFu + ((u>>16)&1u)) >> 16;
}
__device__ __forceinline__ float aload(const float* p){
  return __hip_atomic_load(const_cast<float*>(p), __ATOMIC_RELAXED, MSCOPE);
}
__device__ __forceinline__ float2 aload2(const float* p){
  unsigned long long u = __hip_atomic_load(
      reinterpret_cast<unsigned long long*>(const_cast<float*>(p)),
      __ATOMIC_RELAXED, MSCOPE);
  float2 r; __builtin_memcpy(&r, &u, 8); return r;
}
__device__ __forceinline__ void astore(float* p, float v){
  __hip_atomic_store(p, v, __ATOMIC_RELAXED, MSCOPE);
}
__device__ __forceinline__ void astoreu(unsigned* p, unsigned v){
  __hip_atomic_store(p, v, __ATOMIC_RELAXED, MSCOPE);
}
__device__ __forceinline__ void astore2(float* p, float a, float b){
  float2 t; t.x = a; t.y = b;
  unsigned long long u; __builtin_memcpy(&u, &t, 8);
  __hip_atomic_store(reinterpret_cast<unsigned long long*>(p), u,
                     __ATOMIC_RELAXED, MSCOPE);
}
__device__ __forceinline__ unsigned uload(unsigned* p){
  return __hip_atomic_load(p, __ATOMIC_RELAXED, MSCOPE);
}
__device__ __forceinline__ void set_line(unsigned* line){
  __hip_atomic_store(line, 1u, __ATOMIC_RELAXED, MSCOPE);
}
template<int SLP>
__device__ __forceinline__ void wait_lines(unsigned* base, int n, int tid){
  if (tid < 64){
    for(;;){
      bool miss = (tid < n) && (uload(base + tid*16) == 0u);
      if (__ballot(miss) == 0ULL) break;
      __builtin_amdgcn_s_sleep(SLP);
    }
  }
  __syncthreads();
}
__device__ __forceinline__ void add1(unsigned* word){
  (void)__hip_atomic_fetch_add(word, 1u, __ATOMIC_RELAXED, MSCOPE);
}
__device__ __forceinline__ float block_sum(float v, float* red){
  #pragma unroll
  for (int o=32;o;o>>=1) v += __shfl_down(v,o);
  if ((threadIdx.x&63)==0) red[threadIdx.x>>6] = v;
  __syncthreads();
  v = red[0]+red[1]+red[2]+red[3];
  __syncthreads();
  return v;
}

// ---------------- prep: id mapping + flag/hdF zeroing ----------------
__global__ void prep_kernel(const int* __restrict__ in_ids, const int* __restrict__ tgt,
                            int* __restrict__ in_mapped, int* __restrict__ cur_ids,
                            unsigned* __restrict__ flags, float* __restrict__ hdF){
  const int g0 = blockIdx.x*256 + threadIdx.x, stride = gridDim.x*256;
  for (int i = g0; i < 8192; i += stride){
    int t = i >> 5, b = i & 31;
    int id = in_ids[b*256 + t];
    in_mapped[i] = (id >= 50000) ? 3 : id;
  }
  for (int i = g0; i < 3200; i += stride){
    int k = i >> 5, b = i & 31;
    int id = (k == 0) ? 1 : tgt[b*100 + (k-1)];
    cur_ids[i] = (id >= 50000) ? 3 : id;
  }
  for (int i = g0; i < fEnd; i += stride) flags[i] = 0u;
  for (int i = g0; i < 358400; i += stride) hdF[i] = 0.f;
}

// ------- rowgemm: gather emb rows, write TRANSPOSED out[(t*N+g)*32+b] ---------
struct RGArgs{ const int* gid; const float* emb; const float* W;
               const float* bias1; const float* bias2; float* out; int N; };
__global__ void __launch_bounds__(256) rowgemm(RGArgs a){
  __shared__ float rl[8*128];
  const int tid = threadIdx.x;
  const int N = a.N;
  const size_t r0 = (size_t)blockIdx.x*8;
  const size_t t = r0 >> 5; const int b0 = (int)(r0 & 31);
  for (int i = tid; i < 8*128; i += 256){
    int r = i >> 7, k = i & 127;
    rl[i] = a.emb[(size_t)a.gid[r0+r]*128 + k];
  }
  __syncthreads();
  for (int g = tid; g < N; g += 256){
    const float* wr = a.W + (size_t)g*128;
    float acc[8];
    #pragma unroll
    for (int r=0;r<8;r++) acc[r]=0.f;
    for (int k=0;k<128;k+=4){
      float4 wv = *(const float4*)(wr+k);
      #pragma unroll
      for (int r=0;r<8;r++){
        float4 xv = *(const float4*)(rl + r*128 + k);
        acc[r] += wv.x*xv.x + wv.y*xv.y + wv.z*xv.z + wv.w*xv.w;
      }
    }
    float bias = a.bias1[g] + a.bias2[g];
    float* op = a.out + ((size_t)t*N + g)*32 + b0;
    *(float4*)(op)   = make_float4(acc[0]+bias,acc[1]+bias,acc[2]+bias,acc[3]+bias);
    *(float4*)(op+4) = make_float4(acc[4]+bias,acc[5]+bias,acc[6]+bias,acc[7]+bias);
  }
}

// ====== enc_mega: blocks 0-39 encoder | 40-439 Xd-rowgemm | 440-803 pack_af
//        | 804-873 W1cT | 874-1673 es.  All extras independent of enc chain. ===
struct MegaArgs{
  const float* Xf; const float* Xb; const float* Whf; const float* Whb;
  float* hencB; float* cT; unsigned* flg;
  const int* cur_ids; const float* emb;
  const float* Wi_d; const float* bi_d; const float* bh_d; float* Xd;
  const float* Whd; float* AFl;
  const float* Wda; const float* W1; const float* Wds; float* AFa;
  float* W1cT;
  const float* Wes; float* es;
};

__global__ void __launch_bounds__(256) enc_mega(MegaArgs a){
  extern __shared__ float sm[];
  const int blk = blockIdx.x, tid = threadIdx.x;

  if (blk < 40){
    // ---------------- encoder chain (R13-exact) ----------------
    float* Wl = sm;           // 5120
    float* hl = sm + 5120;    // 32 x 164
    const int dir = blk/20, jwg = blk%20;
    const int b = tid & 31, jl = tid >> 5;
    const int j = jwg*8 + jl;
    const float* Wh = dir ? a.Whb : a.Whf;
    const float* X  = dir ? a.Xb  : a.Xf;
    float* HB = a.hencB + (size_t)dir*32*256*160;
    unsigned* flg = a.flg;
    for (int i = tid; i < 32*160; i += 256){
      int row = i/160, k = i - row*160;
      int gate = row >> 3, jj = row & 7;
      Wl[i] = Wh[((size_t)(gate*160 + jwg*8 + jj))*160 + k];
    }
    for (int i = tid; i < 32*164; i += 256) hl[i] = 0.f;
    float c = 0.f;
    const float4* w0 = (const float4*)(Wl + (0*8+jl)*160);
    const float4* w1 = (const float4*)(Wl + (1*8+jl)*160);
    const float4* w2 = (const float4*)(Wl + (2*8+jl)*160);
    const float4* w3 = (const float4*)(Wl + (3*8+jl)*160);
    __syncthreads();
    for (int t = 0; t < 256; ++t){
      const int trow = dir ? 255 - t : t;
      const float* xr = X + ((size_t)trow*640 + j)*32 + b;
      float g0 = xr[0], g1 = xr[5120], g2 = xr[10240], g3 = xr[15360];
      if (t > 0){
        wait_lines<2>(flg + FENC(dir, t-1, 0), 20, tid);
        const int tprev = dir ? (256 - t) : (t-1);
        for (int i2 = tid; i2 < 2560; i2 += 256){
          int bb = i2/80, kk = (i2 - bb*80)*2;
          float2 v = aload2(HB + ((size_t)bb*256 + tprev)*160 + kk);
          *(float2*)(hl + bb*164 + kk) = v;
        }
      }
      __syncthreads();
      const float4* hr = (const float4*)(hl + b*164);
      #pragma unroll 4
      for (int q = 0; q < 40; ++q){
        float4 hv = hr[q];
        float4 a0 = w0[q], a1 = w1[q], a2 = w2[q], a3 = w3[q];
        g0 += hv.x*a0.x + hv.y*a0.y + hv.z*a0.z + hv.w*a0.w;
        g1 += hv.x*a1.x + hv.y*a1.y + hv.z*a1.z + hv.w*a1.w;
        g2 += hv.x*a2.x + hv.y*a2.y + hv.z*a2.z + hv.w*a2.w;
        g3 += hv.x*a3.x + hv.y*a3.y + hv.z*a3.z + hv.w*a3.w;
      }
      float ig = sigm(g0), fg = sigm(g1), gc = fast_tanh(g2), og = sigm(g3);
      c = fg*c + ig*gc;
      float h = og * fast_tanh(c);
      astore(&HB[((size_t)b*256 + trow)*160 + j], h);
      __syncthreads();
      if (tid == 0) set_line(flg + FENC(dir, t, jwg));
    }
    a.cT[dir*5120 + b*160 + j] = c;
    return;
  }

  if (blk < 440){
    // ---------------- Xd rowgemm (N=784) ----------------
    float* rl = sm;   // 8 x 128
    const size_t r0 = (size_t)(blk - 40)*8;
    const size_t t = r0 >> 5; const int b0 = (int)(r0 & 31);
    for (int i = tid; i < 8*128; i += 256){
      int r = i >> 7, k = i & 127;
      rl[i] = a.emb[(size_t)a.cur_ids[r0+r]*128 + k];
    }
    __syncthreads();
    for (int g = tid; g < 784; g += 256){
      const float* wr = a.Wi_d + (size_t)g*128;
      float acc[8];
      #pragma unroll
      for (int r=0;r<8;r++) acc[r]=0.f;
      for (int k=0;k<128;k+=4){
        float4 wv = *(const float4*)(wr+k);
        #pragma unroll
        for (int r=0;r<8;r++){
          float4 xv = *(const float4*)(rl + r*128 + k);
          acc[r] += wv.x*xv.x + wv.y*xv.y + wv.z*xv.z + wv.w*xv.w;
        }
      }
      float bias = a.bi_d[g] + a.bh_d[g];
      float* op = a.Xd + ((size_t)t*784 + g)*32 + b0;
      *(float4*)(op)   = make_float4(acc[0]+bias,acc[1]+bias,acc[2]+bias,acc[3]+bias);
      *(float4*)(op+4) = make_float4(acc[4]+bias,acc[5]+bias,acc[6]+bias,acc[7]+bias);
    }
    return;
  }

  if (blk < 804){
    // ---------------- pack_af ----------------
    int dw = (blk - 440)*256 + tid;
    if (dw < 93184){
      int frag = dw>>2, d = dw&3;
      int T = frag/448, r2 = frag - T*448;
      int k7 = r2>>6, l = r2&63;
      int jb = T>>2, gate = T&3;
      int j = jb*16 + (l&15);
      int k0 = k7*32 + ((l>>4)<<3) + 2*d;
      unsigned lo=0, hi=0;
      if (j < 196){
        if (k0   < 196) lo = bfr(a.Whd[(size_t)(gate*196+j)*196 + k0]);
        if (k0+1 < 196) hi = bfr(a.Whd[(size_t)(gate*196+j)*196 + k0+1]);
      }
      ((unsigned*)a.AFl)[dw] = lo | (hi<<16);
    }
    if (dw < 32256){
      int frag = dw>>2, d = dw&3;
      int T = frag/448, r2 = frag - T*448;
      int k7 = r2>>6, l = r2&63;
      int ar = T*16 + (l&15);
      int k0 = k7*32 + ((l>>4)<<3) + 2*d;
      unsigned lo=0, hi=0;
      #pragma unroll
      for (int h = 0; h < 2; ++h){
        int k = k0 + h;
        float v = 0.f;
        if (k < 196){
          if (ar < 224) v = a.Wda[(size_t)ar*196 + k];
          else { int g = ar - 224;
            if (g < 56) v = a.W1[(size_t)g*516 + k];
            else if (g == 56) v = a.Wds[k];
          }
        }
        if (h == 0) lo = bfr(v); else hi = bfr(v);
      }
      ((unsigned*)a.AFa)[dw] = lo | (hi<<16);
    }
    return;
  }

  if (blk < 874){
    // ---------------- W1cT ----------------
    int i = (blk - 804)*256 + tid;
    if (i < 17920){ int q = i / 56, g = i - q*56; a.W1cT[q*56+g] = a.W1[(size_t)g*516 + 196 + q]; }
    return;
  }

  // ---------------- es: 4 rows per block ----------------
  {
    int r = (blk - 874)*4 + (tid >> 6);
    int l = tid & 63;
    if (r < 3200){
      const float* e = a.emb + (size_t)a.cur_ids[r]*128;
      float acc = e[l]*a.Wes[l] + e[l+64]*a.Wes[l+64];
      #pragma unroll
      for (int o=32;o;o>>=1) acc += __shfl_down(acc,o);
      if (l==0) a.es[r] = acc;
    }
  }
}

// ---------------- mid: h0/c0 projections ----------------
__global__ void mid_kernel(const float* __restrict__ hencB, const float* __restrict__ cT,
                           const float* __restrict__ Weh, const float* __restrict__ beh,
                           const float* __restrict__ Wec, const float* __restrict__ bec,
                           float* __restrict__ h0, float* __restrict__ c0){
  __shared__ float hc[320], cc[320];
  int b = blockIdx.x, tid = threadIdx.x;
  if (tid < 160){
    hc[tid]     = hencB[((size_t)b*256 + 255)*160 + tid];
    hc[160+tid] = hencB[((size_t)(32+b)*256 + 0)*160 + tid];
    cc[tid]     = cT[b*160 + tid];
    cc[160+tid] = cT[5120 + b*160 + tid];
  }
  __syncthreads();
  for (int g = tid; g < 196; g += 256){
    const float* w1 = Weh + (size_t)g*320;
    const float* w2 = Wec + (size_t)g*320;
    float a1 = beh[g], a2 = bec[g];
    for (int k = 0; k < 320; ++k){ a1 += hc[k]*w1[k]; a2 += cc[k]*w2[k]; }
    h0[b*196 + g] = a1;
    c0[b*196 + g] = a2;
  }
}

// ---------------- encA = [hf;hb] @ Wea.T + bea ----------------
__global__ void __launch_bounds__(256) encA_gemm(const float* __restrict__ hencB,
                 const float* __restrict__ Wea, const float* __restrict__ bea,
                 float* __restrict__ encA){
  __shared__ float rl[8*320];
  const int tid = threadIdx.x;
  const size_t r0 = (size_t)blockIdx.x*8;
  for (int i = tid; i < 8*320; i += 256){
    int r = i/320, k = i - r*320;
    size_t row = r0 + r; int b = (int)(row >> 8), t = (int)(row & 255);
    rl[i] = (k < 160) ? hencB[((size_t)b*256 + t)*160 + k]
                      : hencB[((size_t)(32+b)*256 + t)*160 + (k-160)];
  }
  __syncthreads();
  for (int g = tid; g < 224; g += 256){
    const float* wr = Wea + (size_t)g*320;
    float acc[8];
    #pragma unroll
    for (int r=0;r<8;r++) acc[r]=0.f;
    for (int k=0;k<320;k+=4){
      float4 wv = *(const float4*)(wr+k);
      #pragma unroll
      for (int r=0;r<8;r++){
        float4 xv = *(const float4*)(rl + r*320 + k);
        acc[r] += wv.x*xv.x + wv.y*xv.y + wv.z*xv.z + wv.w*xv.w;
      }
    }
    float bias = bea[g];
    #pragma unroll
    for (int r=0;r<8;r++) encA[(r0+r)*224 + g] = acc[r] + bias;
  }
}

// ---------------- decoder pipeline (REGULAR launch, grid=256) ----------------
// wg 0-7: L-WGs (MFMA LSTM+aux) | wg 8-39: P2 (b=wg-8) | wg 40-255: P3 (216)
struct DecArgs{
  const float* Xd; const float* hencB; const float* encA;
  const float* h0; const float* c0; const float* AFl; const float* AFa;
  float* hdF;
  const float* Wca; const float* vat; const float* W1cT; const float* b1;
  const float* W2; const float* b2;
  const float* Wcs; const float* bcs; const float* es;
  const int* in_ids; const int* tgt;
  float* uAll; float* uPreAll; float* hwdaAll;
  float* hWdsAll; float* ctxWAll; float* copyAll;
  float* zidxAll; float* partAll; float* clAll; float* nllWg; float* out;
  unsigned* flg;
};

__global__ void __launch_bounds__(256) dec_scan(DecArgs A){
  extern __shared__ float sm[];
  const int wg = blockIdx.x, tid = threadIdx.x;
  unsigned* flg = A.flg;

  if (wg < 8){
    // ======== L-WG q: MFMA LSTM (its jb-units) + aux tiles, weights in LDS ====
    const int q = wg;
    const int nUq  = (q < 5) ? 2 : 1;
    const int jb0q = q;
    const int jb1q = (q < 5) ? q + 8 : 0;
    const int auxB = (q < 5) ? q : (q == 5 ? 5 : (q == 6 ? 9 : 13));
    const int auxC = (q < 5) ? 1 : (q == 7 ? 5 : 4);
    unsigned* ldsu = (unsigned*)sm;
    bf16x8*   ldsf = (bf16x8*)sm;
    const int AB = nUq*1792;                    // aux slot base (bf16x8 slots)
    const int l = tid & 63, wv = tid >> 6;
    const int lq = l >> 4, lc = l & 15;
    const int u = wv >> 1, nt = wv & 1;
    const bool act = u < nUq;
    const int jb = (u == 0) ? jb0q : jb1q;
    // ---- copy A-frags into LDS (one-time) ----
    {
      const unsigned* aflu = (const unsigned*)A.AFl;
      const unsigned* afau = (const unsigned*)A.AFa;
      const int totDw = (AB + auxC*448)*4;
      for (int i = tid; i < totDw; i += 256){
        int slot = i>>2, d = i&3;
        unsigned v;
        if (slot < AB){
          int uu = slot/1792, r = slot - uu*1792;
          int fi = r>>6, ll = r&63;             // fi = g*7+k7
          int jbu = (uu == 0) ? jb0q : jb1q;
          int T = jbu*4 + fi/7, k7 = fi%7;
          v = aflu[(((size_t)T*7 + k7)*64 + ll)*4 + d];
        } else {
          int r = slot - AB;
          int a = r/448, r2 = r - a*448;
          int k7 = r2>>6, ll = r2&63;
          v = afau[((((size_t)(auxB + a))*7 + k7)*64 + ll)*4 + d];
        }
        ldsu[i] = v;
      }
    }
    // ---- init c-state + B-fragments from h0/c0 ----
    float cst[4];
    if (act){
      int b = nt*16 + lc;
      #pragma unroll
      for (int i = 0; i < 4; ++i){
        int j = jb*16 + lq*4 + i;
        cst[i] = (j < 196) ? A.c0[b*196 + j] : 0.f;
      }
    }
    bf16x8 Bfr[7][2];
    #pragma unroll
    for (int k7 = 0; k7 < 7; ++k7)
      #pragma unroll
      for (int ntt = 0; ntt < 2; ++ntt){
        short tmp[8];
        #pragma unroll
        for (int e = 0; e < 8; ++e){
          int k = k7*32 + lq*8 + e;
          int b = ntt*16 + lc;
          float hv = (k < 196) ? A.h0[b*196 + k] : 0.f;
          tmp[e] = (short)bfr(hv);
        }
        __builtin_memcpy(&Bfr[k7][ntt], tmp, 16);
      }
    __syncthreads();
    unsigned* hdF = (unsigned*)A.hdF;
    for (int s = 0; s < 100; ++s){
      const float* Xs = A.Xd + (size_t)s*25088;
      if (act){
        float xg4[4][4];
        #pragma unroll
        for (int g = 0; g < 4; ++g)
          #pragma unroll
          for (int i = 0; i < 4; ++i){
            int j = jb*16 + lq*4 + i;
            int b = nt*16 + lc;
            xg4[g][i] = (j < 196) ? Xs[((size_t)(g*196 + j))*32 + b] : 0.f;
          }
        f32x4 acc[4];
        #pragma unroll
        for (int g = 0; g < 4; ++g){
          f32x4 a0 = {0.f,0.f,0.f,0.f};
          #pragma unroll
          for (int k7 = 0; k7 < 7; ++k7){
            bf16x8 af = ldsf[(u*28 + g*7 + k7)*64 + l];
            a0 = __builtin_amdgcn_mfma_f32_16x16x32_bf16(af, Bfr[k7][nt], a0, 0,0,0);
          }
          acc[g] = a0;
        }
        float hv4[4];
        #pragma unroll
        for (int i = 0; i < 4; ++i){
          float I = acc[0][i]+xg4[0][i], F = acc[1][i]+xg4[1][i];
          float G = acc[2][i]+xg4[2][i], O = acc[3][i]+xg4[3][i];
          float cc = sigm(F)*cst[i] + sigm(I)*fast_tanh(G);
          cst[i] = cc;
          hv4[i] = sigm(O)*fast_tanh(cc);
        }
        #pragma unroll
        for (int p = 0; p < 2; ++p){
          int jp = jb*16 + lq*4 + 2*p;
          if (jp < 196){
            int k7 = jp>>5, tl = lc | (((jp>>3)&3)<<4), d = (jp&7)>>1;
            unsigned w = bfr(hv4[2*p]) | (bfr(hv4[2*p+1])<<16);
            astoreu(&hdF[(size_t)s*3584 + ((k7*2+nt)*64 + tl)*4 + d], w);
          }
        }
      }
      __syncthreads();               // drain h stores
      if (tid == 0) set_line(flg + FLSTM(s, q));
      wait_lines<1>(flg + FLSTM(s, 0), 8, tid);
      // reload B fragments = h(s)
      {
        const float* hp = (const float*)(hdF + (size_t)s*3584);
        #pragma unroll
        for (int k7 = 0; k7 < 7; ++k7)
          #pragma unroll
          for (int ntt = 0; ntt < 2; ++ntt){
            float2 v0 = aload2(hp + (((k7*2+ntt)*64 + l)*4));
            float2 v1 = aload2(hp + (((k7*2+ntt)*64 + l)*4 + 2));
            unsigned dwv[4];
            __builtin_memcpy(dwv, &v0, 8); __builtin_memcpy(dwv+2, &v1, 8);
            __builtin_memcpy(&Bfr[k7][ntt], dwv, 16);
          }
      }
      // aux MFMA: wave wv handles a = wv, wv+4
      for (int a = wv; a < auxC; a += 4){
        int T = auxB + a;
        #pragma unroll
        for (int ntt = 0; ntt < 2; ++ntt){
          f32x4 acc = {0.f,0.f,0.f,0.f};
          #pragma unroll
          for (int k7 = 0; k7 < 7; ++k7){
            bf16x8 af = ldsf[AB + (a*7 + k7)*64 + l];
            acc = __builtin_amdgcn_mfma_f32_16x16x32_bf16(af, Bfr[k7][ntt], acc, 0,0,0);
          }
          int b = ntt*16 + lc;
          #pragma unroll
          for (int p = 0; p < 2; ++p){
            int ar = T*16 + lq*4 + 2*p;
            float v0 = acc[2*p], v1 = acc[2*p+1];
            if (ar < 224){
              astore2(&A.hwdaAll[(size_t)s*7168 + b*224 + ar], v0, v1);
            } else {
              int g = ar - 224;
              if (g < 56) astore2(&A.uPreAll[(size_t)s*1792 + b*56 + g], v0, v1);
              else if (g == 56) astore(&A.hWdsAll[s*32 + b], v0);
            }
          }
        }
      }
      __syncthreads();               // drain aux stores
      if (tid == 0) set_line(flg + FAUX(s, q));
    }
    return;
  }

  if (wg < 40){
    // ======== P2: attention + ctx + u (32 WGs, b = wg-8) ========
    const int b = wg - 8;
    float* hwdaL = sm;           // 224
    float* attnL = sm + 224;     // 256
    float* pctx  = sm + 480;     // 960
    float* ctxL  = sm + 1440;    // 320
    float* red   = sm + 1760;    // 4
    float* pu    = sm + 1764;    // 224
    float* wcaL  = sm + 1988;    // 224
    float* vL    = sm + 2212;    // 224
    float* WcsL  = sm + 2436;    // 320
    float* b1L   = sm + 2756;    // 56
    if (tid < 224){ wcaL[tid] = A.Wca[tid]; vL[tid] = A.vat[tid]; }
    for (int i = tid; i < 320; i += 256) WcsL[i] = A.Wcs[i];
    if (tid < 56) b1L[tid] = A.b1[tid];
    const int inid = A.in_ids[b*256 + tid];
    const float4* erow = (const float4*)(A.encA + (size_t)(b*256 + tid)*224);
    float cov = 0.f, clr = 0.f;
    __syncthreads();
    for (int s = 0; s < 100; ++s){
      wait_lines<2>(flg + FAUX(s, 0), 8, tid);
      if (tid < 224) hwdaL[tid] = aload(&A.hwdaAll[(size_t)s*7168 + b*224 + tid]);
      __syncthreads();
      float exv = 0.f;
      if (inid != 0){
        float acc = 0.f;
        #pragma unroll 8
        for (int q = 0; q < 56; ++q){
          float4 ev = erow[q]; int a0 = 4*q;
          acc += fast_tanh(ev.x + hwdaL[a0]   + cov*wcaL[a0]  )*vL[a0];
          acc += fast_tanh(ev.y + hwdaL[a0+1] + cov*wcaL[a0+1])*vL[a0+1];
          acc += fast_tanh(ev.z + hwdaL[a0+2] + cov*wcaL[a0+2])*vL[a0+2];
          acc += fast_tanh(ev.w + hwdaL[a0+3] + cov*wcaL[a0+3])*vL[a0+3];
        }
        exv = __expf(acc);
      }
      float S = block_sum(exv, red);
      float attn = exv * __builtin_amdgcn_rcpf(S);
      attnL[tid] = attn;
      const int ntb = A.tgt[b*100 + s];
      float cpS = block_sum((inid == ntb) ? attn : 0.f, red);
      float mnS = block_sum(fminf(attn, cov), red);
      if (tid == 0){
        astore(&A.copyAll[s*32 + b], cpS);
        clr += mnS;
        if (s == 99) astore(&A.clAll[b], clr);
      }
      cov += attn;
      if (tid < 240){
        int seg = tid/80, h4i = tid - seg*80;
        int t0 = seg*86, t1 = (t0+86 < 256) ? t0+86 : 256;
        const float* base = (h4i < 40)
          ? (A.hencB + ((size_t)b*256)*160 + (size_t)h4i*4)
          : (A.hencB + ((size_t)(32+b)*256)*160 + (size_t)(h4i-40)*4);
        float4 accv = {0.f,0.f,0.f,0.f};
        #pragma unroll 4
        for (int t2 = t0; t2 < t1; ++t2){
          float av = attnL[t2];
          float4 ev = *(const float4*)(base + (size_t)t2*160);
          accv.x += av*ev.x; accv.y += av*ev.y; accv.z += av*ev.z; accv.w += av*ev.w;
        }
        *(float4*)(pctx + (seg*80+h4i)*4) = accv;
      }
      __syncthreads();
      if (tid < 80){
        float4 p0 = *(float4*)(pctx + tid*4);
        float4 p1 = *(float4*)(pctx + (80+tid)*4);
        float4 p2v = *(float4*)(pctx + (160+tid)*4);
        float4 cvv;
        cvv.x = p0.x+p1.x+p2v.x; cvv.y = p0.y+p1.y+p2v.y;
        cvv.z = p0.z+p1.z+p2v.z; cvv.w = p0.w+p1.w+p2v.w;
        *(float4*)(ctxL + tid*4) = cvv;
      }
      __syncthreads();
      if (tid < 224){
        int g = tid % 56, seg = tid / 56;
        float acc = 0.f;
        const float* wp = A.W1cT + (size_t)seg*80*56 + g;
        #pragma unroll 4
        for (int q = 0; q < 80; ++q) acc += ctxL[seg*80 + q] * wp[q*56];
        pu[seg*56 + g] = acc;
      } else {
        int l = tid - 224; float acc = 0.f;
        for (int q = l; q < 320; q += 32) acc += ctxL[q]*WcsL[q];
        #pragma unroll
        for (int o=16;o;o>>=1) acc += __shfl_down(acc,o,32);
        if (l==0) astore(&A.ctxWAll[s*32 + b], acc);
      }
      __syncthreads();
      if (tid < 56){
        float upre = aload(&A.uPreAll[(size_t)s*1792 + b*56 + tid]);
        float uu = fast_tanh(upre + b1L[tid] + pu[tid] + pu[56+tid] + pu[112+tid] + pu[168+tid]);
        astore(&A.uAll[(size_t)s*1792 + b*56 + tid], uu);
      }
      __syncthreads();
      if (tid == 0){
        set_line(flg + FP2(s,0,b));
        set_line(flg + FP2(s,1,b));
        set_line(flg + FP2(s,2,b));
        set_line(flg + FP2(s,3,b));
      }
    }
    return;
  }

  // ======== P3: vocab sum-exp, W2 rows pinned in registers (216 WGs) ========
  {
    const int wgv = wg - 40;
    const int vs = (int)(((long long)wgv*49998)/216);
    const int ve = (int)(((long long)(wgv+1)*49998)/216);
    const int v = vs + tid;
    const bool valid = v < ve;
    const int vc = valid ? v : 0;
    float4 w2r[14];
    {
      const float4* wr = (const float4*)(A.W2 + (size_t)vc*56);
      #pragma unroll
      for (int q=0;q<14;++q) w2r[q] = wr[q];
    }
    const float b2v = A.b2[vc];
    float* ulL  = sm;                  // 1792
    float* redW = sm + 1792;           // 128
    int*   idxL = (int*)(sm + 1920);   // 32
    float* red  = sm + 1952;           // 4
    const int lane = tid & 63, wv2 = tid >> 6;
    for (int s = 0; s < 100; ++s){
      int nt3 = (tid < 32) ? A.tgt[tid*100 + s] : 0;
      wait_lines<8>(flg + FP2(s, wgv & 3, 0), 32, tid);
      for (int i2 = tid; i2 < 896; i2 += 256){
        float2 u2 = aload2(&A.uAll[(size_t)s*1792 + i2*2]);
        *(float2*)(ulL + i2*2) = u2;
      }
      if (tid < 32){
        int ix = nt3 - 2; ix = ix<0?0:(ix>49997?49997:ix);
        idxL[tid] = ix;
      }
      __syncthreads();
      #pragma unroll 4
      for (int bb=0; bb<32; ++bb){
        const float4* uv = (const float4*)(ulL + bb*56);
        float z = b2v;
        #pragma unroll
        for (int q=0;q<14;++q){
          float4 u4 = uv[q];
          z += w2r[q].x*u4.x + w2r[q].y*u4.y + w2r[q].z*u4.z + w2r[q].w*u4.w;
        }
        if (valid && v == idxL[bb]) astore(&A.zidxAll[s*32+bb], z);
        float sv2 = valid ? __expf(z) : 0.f;
        #pragma unroll
        for (int o=32;o;o>>=1) sv2 += __shfl_down(sv2,o);
        if (lane == 0) redW[wv2*32+bb] = sv2;
      }
      __syncthreads();
      if (tid < 32){
        float tot = redW[tid]+redW[32+tid]+redW[64+tid]+redW[96+tid];
        astore(&A.partAll[(size_t)(s*32+tid)*216 + wgv], tot);
      }
      __syncthreads();
    }
    __syncthreads();
    if (tid == 0) add1(flg + CP3);
    if (tid == 0){
      while (uload(flg + CP3) != 216u) __builtin_amdgcn_s_sleep(32);
    }
    __syncthreads();
    float nll1 = 0.f;
    for (int p = wgv; p < 3200; p += 216){
      float pv = (tid < 216) ? aload(&A.partAll[(size_t)p*216 + tid]) : 0.f;
      float se = block_sum(pv, red);
      if (tid == 0){
        int s = p >> 5, b = p & 31;
        int nt2 = A.tgt[b*100 + s];
        float xg = aload(&A.ctxWAll[p]) + A.bcs[0] + aload(&A.hWdsAll[p]) + A.es[p];
        float pg = 1.f/(1.f + __expf(-xg));
        float genp = (nt2 >= 2 && nt2 < 50000) ? (__expf(aload(&A.zidxAll[p])) / se) : 0.f;
        float pr = pg*genp + (1.f-pg)*aload(&A.copyAll[p]);
        nll1 += -logf(pr + 1e-9f);
      }
    }
    if (tid == 0) astore(&A.nllWg[wgv], nll1);
    __syncthreads();
    if (tid == 0) add1(flg + CFIN);
    if (wg == 40){
      if (tid == 0){
        while (uload(flg + CFIN) != 216u) __builtin_amdgcn_s_sleep(32);
      }
      __syncthreads();
      float nv = (tid < 216) ? aload(&A.nllWg[tid]) : 0.f;
      float nll = block_sum(nv, red);
      float cv = (tid < 32) ? aload(&A.clAll[tid]) : 0.f;
      float cl = block_sum(cv, red);
      if (tid == 0){ A.out[0]=nll; A.out[1]=cl; A.out[2]=nll + 0.75f*cl; }
    }
  }
}

// ---------------- host launch ----------------
extern "C" void kernel_launch(void* const* d_in, const int* in_sizes, int n_in,
                              void* d_out, int out_size, void* d_ws, size_t ws_size,
                              hipStream_t stream){
  const int*   in_ids = (const int*)  d_in[0];
  const int*   tgt    = (const int*)  d_in[1];
  const float* emb    = (const float*)d_in[3];
  const float* Wi_f   = (const float*)d_in[4];
  const float* Wh_f   = (const float*)d_in[5];
  const float* bi_f   = (const float*)d_in[6];
  const float* bh_f   = (const float*)d_in[7];
  const float* Wi_b   = (const float*)d_in[8];
  const float* Wh_b   = (const float*)d_in[9];
  const float* bi_b   = (const float*)d_in[10];
  const float* bh_b   = (const float*)d_in[11];
  const float* Weh    = (const float*)d_in[12];
  const float* beh    = (const float*)d_in[13];
  const float* Wec    = (const float*)d_in[14];
  const float* bec    = (const float*)d_in[15];
  const float* Wi_d   = (const float*)d_in[16];
  const float* Wh_d   = (const float*)d_in[17];
  const float* bi_d   = (const float*)d_in[18];
  const float* bh_d   = (const float*)d_in[19];
  const float* Wea    = (const float*)d_in[20];
  const float* bea    = (const float*)d_in[21];
  const float* Wda    = (const float*)d_in[22];
  const float* Wca    = (const float*)d_in[23];
  const float* vat    = (const float*)d_in[24];
  const float* W1     = (const float*)d_in[25];
  const float* b1     = (const float*)d_in[26];
  const float* W2     = (const float*)d_in[27];
  const float* b2     = (const float*)d_in[28];
  const float* Wcs    = (const float*)d_in[29];
  const float* bcs    = (const float*)d_in[30];
  const float* Wds    = (const float*)d_in[31];
  const float* Wes    = (const float*)d_in[32];

  float* ws = (float*)d_ws;
  int* iBase = (int*)(ws + oFEnd);
  int* in_mapped = iBase;
  int* cur_ids   = iBase + 8192;
  unsigned* flags = (unsigned*)(iBase + 11392);

  prep_kernel<<<512, 256, 0, stream>>>(in_ids, tgt, in_mapped, cur_ids, flags,
                                       ws + oHdF);

  { RGArgs a{in_mapped, emb, Wi_f, bi_f, bh_f, ws + oXf, 640};
    rowgemm<<<1024, 256, 0, stream>>>(a); }
  { RGArgs a{in_mapped, emb, Wi_b, bi_b, bh_b, ws + oXb, 640};
    rowgemm<<<1024, 256, 0, stream>>>(a); }

  { MegaArgs ma{ws + oXf, ws + oXb, Wh_f, Wh_b, ws + oHencB, ws + oCT, flags,
                cur_ids, emb, Wi_d, bi_d, bh_d, ws + oXd,
                Wh_d, ws + oAFl, Wda, W1, Wds, ws + oAFa,
                ws + oW1cT, Wes, ws + oEs};
    enc_mega<<<dim3(1674), dim3(256), (5120 + 32*164)*4, stream>>>(ma); }

  mid_kernel<<<32, 256, 0, stream>>>(ws + oHencB, ws + oCT, Weh, beh, Wec, bec,
                                     ws + oH0, ws + oC0);

  encA_gemm<<<1024, 256, 0, stream>>>(ws + oHencB, Wea, bea, ws + oEncA);

  { DecArgs da{ws + oXd, ws + oHencB, ws + oEncA,
               ws + oH0, ws + oC0, ws + oAFl, ws + oAFa,
               ws + oHdF,
               Wca, vat, ws + oW1cT, b1, W2, b2, Wcs, bcs, ws + oEs,
               in_ids, tgt,
               ws + oUAll, ws + oUPreAll, ws + oHwdaAll,
               ws + oHWdsAll, ws + oCtxWAll, ws + oCopyAll,
               ws + oZidxAll, ws + oPartAll, ws + oClAll, ws + oNllWg, (float*)d_out,
               flags};
    dec_scan<<<dim3(256), dim3(256), 64512, stream>>>(da); }
}